// Round 2
// baseline (2782.506 us; speedup 1.0000x reference)
//
#include <hip/hip_runtime.h>
#include <hip/hip_cooperative_groups.h>
#include <stdint.h>

#define THR 10.0f

// ---- workspace layout (bytes) ----
// s1 (u8): 8*4*256*256 = 2,097,152  at 0
// p2 (u8): 8*36*21*21  =   127,008  at 2,097,152

// Persistent cooperative kernel: 512 blocks x 256 threads, 2 blocks/CU.
// m1 state lives in registers (16 f/thread), m2 in registers of blocks 0..287
// (9 f/thread), m3 in 2 regs/wave. Only s1 and p2 round-trip through global.
// Per timestep: phase A = conv1+LIF1+WTA (+ L3(t-1) fused), phase B =
// pool1+conv2+LIF2+WTA+pool2. 2 grid syncs per timestep.
__global__ __launch_bounds__(256, 2) void spike_persist(
    const float* __restrict__ x,    // (20,8,1,256,256)
    const float* __restrict__ w1,   // (4,1,5,5)
    const float* __restrict__ w2,   // (36,4,5,5)
    const float* __restrict__ w3,   // (1,36,7,7)
    float* __restrict__ out,        // (20,8,1,21,21)
    uint8_t* __restrict__ s1,
    uint8_t* __restrict__ p2)
{
    cooperative_groups::grid_group grid = cooperative_groups::this_grid();

    __shared__ float xs[2112];      // 8 rows x 264 cols of x (halo 2)
    __shared__ float ps[576];       // 4 x 12 x 12 pooled p1 tile (halo 2)
    __shared__ float mem_s[2304];   // 36 ch x 64 px
    __shared__ float bm_s[576];     // 36 ch x 16 blocks
    __shared__ int   wc_s[64];      // winner channel per px

    const int tid = threadIdx.x;
    const int bid = blockIdx.x;

    // ---- L1 ownership: 512 blocks = 8 b x 64 row-strips (4 rows each).
    // thread -> one 2x2 WTA block: 2 block-rows x 128 block-cols.
    const int b1 = bid >> 6;
    const int r0 = (bid & 63) * 4;
    const int tr = tid >> 7, tc = tid & 127;
    const int py = r0 + 2 * tr;     // top row of this thread's 2x2
    const int px = 2 * tc;

    // ---- L2 ownership: blocks 0..287 = 8 b x (6x6) tiles of 8x8 px
    const bool l2act = bid < 288;
    const int b2 = bid / 36;
    const int ty2 = (bid % 36) / 6, tx2 = bid % 6;
    const int oy2 = ty2 * 8, ox2 = tx2 * 8;
    const int wave = tid >> 6, lane = tid & 63;
    const int pr = lane >> 3, pc = lane & 7;
    const int gy2 = oy2 + pr, gx2 = ox2 + pc;
    const bool valid2 = (gy2 < 42) && (gx2 < 42);

    // ---- L3 ownership: wave id 0..2047, outputs w and w+2048 (<3528)
    const int wid = bid * 4 + wave;
    const int kyl = lane / 7, kxl = lane % 7;   // lane -> 7x7 kernel pos

    float m1r[4][2][2];
#pragma unroll
    for (int c = 0; c < 4; c++)
#pragma unroll
        for (int dy = 0; dy < 2; dy++)
#pragma unroll
            for (int dx = 0; dx < 2; dx++) m1r[c][dy][dx] = 0.f;
    float m2r[9];
#pragma unroll
    for (int i = 0; i < 9; i++) m2r[i] = 0.f;
    float m3r[2] = {0.f, 0.f};

    for (int t = 0; t < 20; t++) {
        // ================= phase A : L1(t) =================
        const float* xb = x + ((size_t)t * 8 + b1) * 65536;
        for (int idx = tid; idx < 2112; idx += 256) {
            int row = idx / 264, col = idx - row * 264;
            int gy = r0 + row - 2, gx = col - 2;
            float v = 0.f;
            if (gy >= 0 && gy < 256 && gx >= 0 && gx < 256) v = xb[gy * 256 + gx];
            xs[idx] = v;
        }
        __syncthreads();

        float p[6][6];
#pragma unroll
        for (int i = 0; i < 6; i++)
#pragma unroll
            for (int j = 0; j < 6; j++)
                p[i][j] = xs[(2 * tr + i) * 264 + 2 * tc + j];

        float acc[4][2][2];
#pragma unroll
        for (int c = 0; c < 4; c++)
#pragma unroll
            for (int dy = 0; dy < 2; dy++)
#pragma unroll
                for (int dx = 0; dx < 2; dx++) acc[c][dy][dx] = 0.f;
#pragma unroll
        for (int c = 0; c < 4; c++)
#pragma unroll
            for (int ky = 0; ky < 5; ky++)
#pragma unroll
                for (int kx = 0; kx < 5; kx++) {
                    float w = w1[c * 25 + ky * 5 + kx];
#pragma unroll
                    for (int dy = 0; dy < 2; dy++)
#pragma unroll
                        for (int dx = 0; dx < 2; dx++)
                            acc[c][dy][dx] = fmaf(p[dy + ky][dx + kx], w, acc[c][dy][dx]);
                }

        float mem[4][2][2];
#pragma unroll
        for (int c = 0; c < 4; c++)
#pragma unroll
            for (int dy = 0; dy < 2; dy++)
#pragma unroll
                for (int dx = 0; dx < 2; dx++)
                    mem[c][dy][dx] = m1r[c][dy][dx] + acc[c][dy][dx];

        int wc[2][2];
#pragma unroll
        for (int dy = 0; dy < 2; dy++)
#pragma unroll
            for (int dx = 0; dx < 2; dx++) {
                int w = 0; float mx = mem[0][dy][dx];
#pragma unroll
                for (int c = 1; c < 4; c++) {
                    float v = mem[c][dy][dx];
                    if (v > mx) { mx = v; w = c; }
                }
                wc[dy][dx] = w;
            }

        float bm[4];
#pragma unroll
        for (int c = 0; c < 4; c++)
            bm[c] = fmaxf(fmaxf(mem[c][0][0], mem[c][0][1]), fmaxf(mem[c][1][0], mem[c][1][1]));

#pragma unroll
        for (int c = 0; c < 4; c++) {
            size_t base = ((size_t)(b1 * 4 + c)) * 65536 + (size_t)py * 256 + px;
#pragma unroll
            for (int dy = 0; dy < 2; dy++) {
                uchar2 sp;
                {
                    float m = mem[c][dy][0];
                    bool s = (m >= THR) && (wc[dy][0] == c) && (m >= bm[c]);
                    sp.x = s ? 1 : 0;
                    m1r[c][dy][0] = fmaxf((s ? 0.f : m) - 9.0f, 0.f);
                }
                {
                    float m = mem[c][dy][1];
                    bool s = (m >= THR) && (wc[dy][1] == c) && (m >= bm[c]);
                    sp.y = s ? 1 : 0;
                    m1r[c][dy][1] = fmaxf((s ? 0.f : m) - 9.0f, 0.f);
                }
                *reinterpret_cast<uchar2*>(s1 + base + (size_t)dy * 256) = sp;
            }
        }

        // ================= phase A : L3(t-1) =================
        if (t > 0) {
            const int tl = t - 1;
#pragma unroll
            for (int rep = 0; rep < 2; rep++) {
                int o = wid + rep * 2048;
                if (o < 3528) {
                    int bb = o / 441, rem = o - bb * 441;
                    int rr = rem / 21, cl = rem - rr * 21;
                    const uint8_t* pb = p2 + (size_t)bb * 36 * 441;
                    int yy = rr + kyl - 3, xx = cl + kxl - 3;
                    bool inb = (lane < 49) && yy >= 0 && yy < 21 && xx >= 0 && xx < 21;
                    int poff = yy * 21 + xx;
                    float accv = 0.f;
                    for (int c = 0; c < 36; c++) {
                        float wv = 0.f, v = 0.f;
                        if (lane < 49) wv = w3[c * 49 + lane];
                        if (inb) v = (float)pb[c * 441 + poff];
                        accv = fmaf(v, wv, accv);
                    }
#pragma unroll
                    for (int off = 32; off; off >>= 1) accv += __shfl_xor(accv, off, 64);
                    float memv3 = m3r[rep] + accv;
                    bool s = memv3 >= THR;
                    if (lane == 0) out[(size_t)tl * 3528 + o] = s ? 1.f : 0.f;
                    m3r[rep] = fmaxf(s ? 0.f : memv3, 0.f);
                }
            }
        }

        grid.sync();

        // ================= phase B : pool1 + conv2 + LIF2 + WTA + pool2 =================
        if (l2act) {
            for (int idx = tid; idx < 576; idx += 256) {
                int ic = idx / 144, rem = idx - ic * 144;
                int r = rem / 12, cc2 = rem - r * 12;
                int gy = oy2 + r - 2, gx = ox2 + cc2 - 2;
                float v = 0.f;
                if (gy >= 0 && gy < 42 && gx >= 0 && gx < 42) {
                    const uint8_t* base = s1 + ((size_t)(b2 * 4 + ic) * 256 + gy * 6) * 256 + gx * 6;
                    int m = 0;
#pragma unroll
                    for (int dy = 0; dy < 7; dy++)
#pragma unroll
                        for (int dx = 0; dx < 7; dx++) {
                            int u = base[dy * 256 + dx];
                            m = u > m ? u : m;
                        }
                    v = (float)m;
                }
                ps[idx] = v;
            }
            __syncthreads();

            float pv[4][5][5];
#pragma unroll
            for (int ic = 0; ic < 4; ic++)
#pragma unroll
                for (int i = 0; i < 5; i++)
#pragma unroll
                    for (int j = 0; j < 5; j++)
                        pv[ic][i][j] = ps[ic * 144 + (pr + i) * 12 + (pc + j)];

            float memv[9];
            for (int cc = 0; cc < 9; cc++) {
                int c = cc * 4 + wave;                       // wave-uniform
                const float* wr = w2 + (size_t)__builtin_amdgcn_readfirstlane(c) * 100;
                float accv = 0.f;
#pragma unroll
                for (int ic = 0; ic < 4; ic++)
#pragma unroll
                    for (int i = 0; i < 5; i++)
#pragma unroll
                        for (int j = 0; j < 5; j++)
                            accv = fmaf(pv[ic][i][j], wr[ic * 25 + i * 5 + j], accv);
                float m = valid2 ? (m2r[cc] + accv) : -1e30f;
                memv[cc] = m;
                mem_s[c * 64 + lane] = m;
            }
            __syncthreads();

            if (tid < 64) {
                float mx = mem_s[tid]; int w = 0;
                for (int c = 1; c < 36; c++) {
                    float v = mem_s[c * 64 + tid];
                    if (v > mx) { mx = v; w = c; }
                }
                wc_s[tid] = w;
            }
            for (int idx = tid; idx < 576; idx += 256) {
                int c = idx >> 4, blk = idx & 15;
                int l0 = (blk >> 2) * 16 + (blk & 3) * 2;
                float a = mem_s[c * 64 + l0],     bb2 = mem_s[c * 64 + l0 + 1];
                float d = mem_s[c * 64 + l0 + 8], e   = mem_s[c * 64 + l0 + 9];
                bm_s[idx] = fmaxf(fmaxf(a, bb2), fmaxf(d, e));
            }
            __syncthreads();

            // owner update of m2 registers
            const int blkl = (pr >> 1) * 4 + (pc >> 1);
            for (int cc = 0; cc < 9; cc++) {
                int c = cc * 4 + wave;
                if (valid2) {
                    float m = memv[cc];
                    bool s = (m >= THR) && (wc_s[lane] == c) && (m >= bm_s[c * 16 + blkl]);
                    m2r[cc] = fmaxf((s ? 0.f : m) - 1.0f, 0.f);
                }
            }

            // pool2 output (2x2 == WTA block): any spike in block
            for (int idx = tid; idx < 576; idx += 256) {
                int c = idx >> 4, blk = idx & 15;
                int br = blk >> 2, bc2 = blk & 3;
                int l0 = br * 16 + bc2 * 2;
                float bmv = bm_s[idx];
                uint8_t any = 0;
#pragma unroll
                for (int k = 0; k < 4; k++) {
                    int dy = k >> 1, dx = k & 1;
                    int l = l0 + dy * 8 + dx;
                    int py2 = oy2 + 2 * br + dy, px2 = ox2 + 2 * bc2 + dx;
                    if (py2 < 42 && px2 < 42) {
                        float m = mem_s[c * 64 + l];
                        bool s = (m >= THR) && (wc_s[l] == c) && (m >= bmv);
                        any |= (uint8_t)s;
                    }
                }
                int gby = (oy2 >> 1) + br, gbx = (ox2 >> 1) + bc2;
                if (gby < 21 && gbx < 21)
                    p2[((size_t)(b2 * 36 + c) * 21 + gby) * 21 + gbx] = any;
            }
        }

        grid.sync();
    }

    // ================= final L3(19) =================
    {
        const int tl = 19;
#pragma unroll
        for (int rep = 0; rep < 2; rep++) {
            int o = wid + rep * 2048;
            if (o < 3528) {
                int bb = o / 441, rem = o - bb * 441;
                int rr = rem / 21, cl = rem - rr * 21;
                const uint8_t* pb = p2 + (size_t)bb * 36 * 441;
                int yy = rr + kyl - 3, xx = cl + kxl - 3;
                bool inb = (lane < 49) && yy >= 0 && yy < 21 && xx >= 0 && xx < 21;
                int poff = yy * 21 + xx;
                float accv = 0.f;
                for (int c = 0; c < 36; c++) {
                    float wv = 0.f, v = 0.f;
                    if (lane < 49) wv = w3[c * 49 + lane];
                    if (inb) v = (float)pb[c * 441 + poff];
                    accv = fmaf(v, wv, accv);
                }
#pragma unroll
                for (int off = 32; off; off >>= 1) accv += __shfl_xor(accv, off, 64);
                float memv3 = m3r[rep] + accv;
                bool s = memv3 >= THR;
                if (lane == 0) out[(size_t)tl * 3528 + o] = s ? 1.f : 0.f;
            }
        }
    }
}

extern "C" void kernel_launch(void* const* d_in, const int* in_sizes, int n_in,
                              void* d_out, int out_size, void* d_ws, size_t ws_size,
                              hipStream_t stream) {
    const float* x  = (const float*)d_in[0];
    const float* w1 = (const float*)d_in[1];
    const float* w2 = (const float*)d_in[2];
    const float* w3 = (const float*)d_in[3];
    float* out = (float*)d_out;
    uint8_t* s1 = (uint8_t*)d_ws;
    uint8_t* p2 = (uint8_t*)d_ws + 2097152;

    void* args[] = {(void*)&x, (void*)&w1, (void*)&w2, (void*)&w3,
                    (void*)&out, (void*)&s1, (void*)&p2};
    hipLaunchCooperativeKernel((void*)spike_persist, dim3(512), dim3(256),
                               args, 0, stream);
}

// Round 3
// 1653.098 us; speedup vs baseline: 1.6832x; 1.6832x over previous
//
#include <hip/hip_runtime.h>
#include <stdint.h>

#define THR 10.0f

// ---- workspace layout (bytes) ----
// s1 (u8): 8*4*256*256 = 2,097,152  at 0
// p2 (u8): 8*36*21*21  =   127,008  at 2,097,152
// barrier: u32[160] (64B-padded counters) at 2,224,384
static constexpr size_t OFF_P2  = 2097152;
static constexpr size_t OFF_BAR = 2224384;

__global__ __launch_bounds__(256) void zero_bar(uint32_t* __restrict__ bar) {
    if (threadIdx.x < 160) bar[threadIdx.x] = 0u;
}

// Two-level tree barrier, monotonic counters (no reset / no ABA).
// bar[ (bid>>6)*16 ] : 8 group counters (64 arrivals each), 64B apart
// bar[128] : root counter (8 arrivals)   bar[144] : epoch
__device__ __forceinline__ void gbar(uint32_t* bar, int bid, uint32_t nbar) {
    __syncthreads();
    if (threadIdx.x == 0) {
        __threadfence();   // release: agent-scope, L2 writeback
        uint32_t* g = bar + ((bid >> 6) * 16);
        if (__hip_atomic_fetch_add(g, 1u, __ATOMIC_RELAXED,
                                   __HIP_MEMORY_SCOPE_AGENT) == 64u * nbar - 1u) {
            if (__hip_atomic_fetch_add(bar + 128, 1u, __ATOMIC_RELAXED,
                                       __HIP_MEMORY_SCOPE_AGENT) == 8u * nbar - 1u) {
                __hip_atomic_fetch_add(bar + 144, 1u, __ATOMIC_RELEASE,
                                       __HIP_MEMORY_SCOPE_AGENT);
            }
        }
        while (__hip_atomic_load(bar + 144, __ATOMIC_RELAXED,
                                 __HIP_MEMORY_SCOPE_AGENT) < nbar) {
            __builtin_amdgcn_s_sleep(2);
        }
        __threadfence();   // acquire: L1/L2 invalidate before reading remote data
    }
    __syncthreads();
}

// Persistent kernel: 512 blocks x 256 threads, 2 blocks/CU.
// m1 in registers (16 f/thread), m2 in registers of blocks 0..287 (9 f/thread),
// m3 in 2 regs/wave. Only s1 and p2 round-trip through global.
__global__ __launch_bounds__(256, 2) void spike_persist(
    const float* __restrict__ x,    // (20,8,1,256,256)
    const float* __restrict__ w1,   // (4,1,5,5)
    const float* __restrict__ w2,   // (36,4,5,5)
    const float* __restrict__ w3,   // (1,36,7,7)
    float* __restrict__ out,        // (20,8,1,21,21)
    uint8_t* __restrict__ s1,
    uint8_t* __restrict__ p2,
    uint32_t* __restrict__ bar)
{
    __shared__ float xs[2112];      // 8 rows x 264 cols of x (halo 2)
    __shared__ float ps[576];       // 4 x 12 x 12 pooled p1 tile (halo 2)
    __shared__ float mem_s[2304];   // 36 ch x 64 px
    __shared__ float bm_s[576];     // 36 ch x 16 blocks
    __shared__ int   wc_s[64];      // winner channel per px

    const int tid = threadIdx.x;
    const int bid = blockIdx.x;
    uint32_t nbar = 0;

    // ---- L1 ownership: 512 blocks = 8 b x 64 row-strips (4 rows each).
    const int b1 = bid >> 6;
    const int r0 = (bid & 63) * 4;
    const int tr = tid >> 7, tc = tid & 127;
    const int py = r0 + 2 * tr;
    const int px = 2 * tc;

    // ---- L2 ownership: blocks 0..287 = 8 b x (6x6) tiles of 8x8 px
    const bool l2act = bid < 288;
    const int b2 = bid / 36;
    const int ty2 = (bid % 36) / 6, tx2 = bid % 6;
    const int oy2 = ty2 * 8, ox2 = tx2 * 8;
    const int wave = tid >> 6, lane = tid & 63;
    const int pr = lane >> 3, pc = lane & 7;
    const int gy2 = oy2 + pr, gx2 = ox2 + pc;
    const bool valid2 = (gy2 < 42) && (gx2 < 42);

    // ---- L3 ownership: wave id 0..2047, outputs w and w+2048 (<3528)
    const int wid = bid * 4 + wave;
    const int kyl = lane / 7, kxl = lane % 7;

    float m1r[4][2][2];
#pragma unroll
    for (int c = 0; c < 4; c++)
#pragma unroll
        for (int dy = 0; dy < 2; dy++)
#pragma unroll
            for (int dx = 0; dx < 2; dx++) m1r[c][dy][dx] = 0.f;
    float m2r[9];
#pragma unroll
    for (int i = 0; i < 9; i++) m2r[i] = 0.f;
    float m3r[2] = {0.f, 0.f};

    for (int t = 0; t < 20; t++) {
        // ================= phase A : L1(t) =================
        const float* xb = x + ((size_t)t * 8 + b1) * 65536;
        for (int idx = tid; idx < 2112; idx += 256) {
            int row = idx / 264, col = idx - row * 264;
            int gy = r0 + row - 2, gx = col - 2;
            float v = 0.f;
            if (gy >= 0 && gy < 256 && gx >= 0 && gx < 256) v = xb[gy * 256 + gx];
            xs[idx] = v;
        }
        __syncthreads();

        float p[6][6];
#pragma unroll
        for (int i = 0; i < 6; i++)
#pragma unroll
            for (int j = 0; j < 6; j++)
                p[i][j] = xs[(2 * tr + i) * 264 + 2 * tc + j];

        float acc[4][2][2];
#pragma unroll
        for (int c = 0; c < 4; c++)
#pragma unroll
            for (int dy = 0; dy < 2; dy++)
#pragma unroll
                for (int dx = 0; dx < 2; dx++) acc[c][dy][dx] = 0.f;
#pragma unroll
        for (int c = 0; c < 4; c++)
#pragma unroll
            for (int ky = 0; ky < 5; ky++)
#pragma unroll
                for (int kx = 0; kx < 5; kx++) {
                    float w = w1[c * 25 + ky * 5 + kx];
#pragma unroll
                    for (int dy = 0; dy < 2; dy++)
#pragma unroll
                        for (int dx = 0; dx < 2; dx++)
                            acc[c][dy][dx] = fmaf(p[dy + ky][dx + kx], w, acc[c][dy][dx]);
                }

        float mem[4][2][2];
#pragma unroll
        for (int c = 0; c < 4; c++)
#pragma unroll
            for (int dy = 0; dy < 2; dy++)
#pragma unroll
                for (int dx = 0; dx < 2; dx++)
                    mem[c][dy][dx] = m1r[c][dy][dx] + acc[c][dy][dx];

        int wc[2][2];
#pragma unroll
        for (int dy = 0; dy < 2; dy++)
#pragma unroll
            for (int dx = 0; dx < 2; dx++) {
                int w = 0; float mx = mem[0][dy][dx];
#pragma unroll
                for (int c = 1; c < 4; c++) {
                    float v = mem[c][dy][dx];
                    if (v > mx) { mx = v; w = c; }
                }
                wc[dy][dx] = w;
            }

        float bm[4];
#pragma unroll
        for (int c = 0; c < 4; c++)
            bm[c] = fmaxf(fmaxf(mem[c][0][0], mem[c][0][1]), fmaxf(mem[c][1][0], mem[c][1][1]));

#pragma unroll
        for (int c = 0; c < 4; c++) {
            size_t base = ((size_t)(b1 * 4 + c)) * 65536 + (size_t)py * 256 + px;
#pragma unroll
            for (int dy = 0; dy < 2; dy++) {
                uchar2 sp;
                {
                    float m = mem[c][dy][0];
                    bool s = (m >= THR) && (wc[dy][0] == c) && (m >= bm[c]);
                    sp.x = s ? 1 : 0;
                    m1r[c][dy][0] = fmaxf((s ? 0.f : m) - 9.0f, 0.f);
                }
                {
                    float m = mem[c][dy][1];
                    bool s = (m >= THR) && (wc[dy][1] == c) && (m >= bm[c]);
                    sp.y = s ? 1 : 0;
                    m1r[c][dy][1] = fmaxf((s ? 0.f : m) - 9.0f, 0.f);
                }
                *reinterpret_cast<uchar2*>(s1 + base + (size_t)dy * 256) = sp;
            }
        }

        // ================= phase A : L3(t-1) =================
        if (t > 0) {
            const int tl = t - 1;
#pragma unroll
            for (int rep = 0; rep < 2; rep++) {
                int o = wid + rep * 2048;
                if (o < 3528) {
                    int bb = o / 441, rem = o - bb * 441;
                    int rr = rem / 21, cl = rem - rr * 21;
                    const uint8_t* pb = p2 + (size_t)bb * 36 * 441;
                    int yy = rr + kyl - 3, xx = cl + kxl - 3;
                    bool inb = (lane < 49) && yy >= 0 && yy < 21 && xx >= 0 && xx < 21;
                    int poff = yy * 21 + xx;
                    float accv = 0.f;
                    for (int c = 0; c < 36; c++) {
                        float wv = 0.f, v = 0.f;
                        if (lane < 49) wv = w3[c * 49 + lane];
                        if (inb) v = (float)pb[c * 441 + poff];
                        accv = fmaf(v, wv, accv);
                    }
#pragma unroll
                    for (int off = 32; off; off >>= 1) accv += __shfl_xor(accv, off, 64);
                    float memv3 = m3r[rep] + accv;
                    bool s = memv3 >= THR;
                    if (lane == 0) out[(size_t)tl * 3528 + o] = s ? 1.f : 0.f;
                    m3r[rep] = fmaxf(s ? 0.f : memv3, 0.f);
                }
            }
        }

        gbar(bar, bid, ++nbar);

        // ================= phase B : pool1 + conv2 + LIF2 + WTA + pool2 =================
        if (l2act) {
            for (int idx = tid; idx < 576; idx += 256) {
                int ic = idx / 144, rem = idx - ic * 144;
                int r = rem / 12, cc2 = rem - r * 12;
                int gy = oy2 + r - 2, gx = ox2 + cc2 - 2;
                float v = 0.f;
                if (gy >= 0 && gy < 42 && gx >= 0 && gx < 42) {
                    const uint8_t* base = s1 + ((size_t)(b2 * 4 + ic) * 256 + gy * 6) * 256 + gx * 6;
                    int m = 0;
#pragma unroll
                    for (int dy = 0; dy < 7; dy++)
#pragma unroll
                        for (int dx = 0; dx < 7; dx++) {
                            int u = base[dy * 256 + dx];
                            m = u > m ? u : m;
                        }
                    v = (float)m;
                }
                ps[idx] = v;
            }
            __syncthreads();

            float pv[4][5][5];
#pragma unroll
            for (int ic = 0; ic < 4; ic++)
#pragma unroll
                for (int i = 0; i < 5; i++)
#pragma unroll
                    for (int j = 0; j < 5; j++)
                        pv[ic][i][j] = ps[ic * 144 + (pr + i) * 12 + (pc + j)];

            float memv[9];
            for (int cc = 0; cc < 9; cc++) {
                int c = cc * 4 + wave;                       // wave-uniform
                const float* wr = w2 + (size_t)__builtin_amdgcn_readfirstlane(c) * 100;
                float accv = 0.f;
#pragma unroll
                for (int ic = 0; ic < 4; ic++)
#pragma unroll
                    for (int i = 0; i < 5; i++)
#pragma unroll
                        for (int j = 0; j < 5; j++)
                            accv = fmaf(pv[ic][i][j], wr[ic * 25 + i * 5 + j], accv);
                float m = valid2 ? (m2r[cc] + accv) : -1e30f;
                memv[cc] = m;
                mem_s[c * 64 + lane] = m;
            }
            __syncthreads();

            if (tid < 64) {
                float mx = mem_s[tid]; int w = 0;
                for (int c = 1; c < 36; c++) {
                    float v = mem_s[c * 64 + tid];
                    if (v > mx) { mx = v; w = c; }
                }
                wc_s[tid] = w;
            }
            for (int idx = tid; idx < 576; idx += 256) {
                int c = idx >> 4, blk = idx & 15;
                int l0 = (blk >> 2) * 16 + (blk & 3) * 2;
                float a = mem_s[c * 64 + l0],     bb2 = mem_s[c * 64 + l0 + 1];
                float d = mem_s[c * 64 + l0 + 8], e   = mem_s[c * 64 + l0 + 9];
                bm_s[idx] = fmaxf(fmaxf(a, bb2), fmaxf(d, e));
            }
            __syncthreads();

            const int blkl = (pr >> 1) * 4 + (pc >> 1);
            for (int cc = 0; cc < 9; cc++) {
                int c = cc * 4 + wave;
                if (valid2) {
                    float m = memv[cc];
                    bool s = (m >= THR) && (wc_s[lane] == c) && (m >= bm_s[c * 16 + blkl]);
                    m2r[cc] = fmaxf((s ? 0.f : m) - 1.0f, 0.f);
                }
            }

            for (int idx = tid; idx < 576; idx += 256) {
                int c = idx >> 4, blk = idx & 15;
                int br = blk >> 2, bc2 = blk & 3;
                int l0 = br * 16 + bc2 * 2;
                float bmv = bm_s[idx];
                uint8_t any = 0;
#pragma unroll
                for (int k = 0; k < 4; k++) {
                    int dy = k >> 1, dx = k & 1;
                    int l = l0 + dy * 8 + dx;
                    int py2 = oy2 + 2 * br + dy, px2 = ox2 + 2 * bc2 + dx;
                    if (py2 < 42 && px2 < 42) {
                        float m = mem_s[c * 64 + l];
                        bool s = (m >= THR) && (wc_s[l] == c) && (m >= bmv);
                        any |= (uint8_t)s;
                    }
                }
                int gby = (oy2 >> 1) + br, gbx = (ox2 >> 1) + bc2;
                if (gby < 21 && gbx < 21)
                    p2[((size_t)(b2 * 36 + c) * 21 + gby) * 21 + gbx] = any;
            }
        }

        gbar(bar, bid, ++nbar);
    }

    // ================= final L3(19) =================
    {
        const int tl = 19;
#pragma unroll
        for (int rep = 0; rep < 2; rep++) {
            int o = wid + rep * 2048;
            if (o < 3528) {
                int bb = o / 441, rem = o - bb * 441;
                int rr = rem / 21, cl = rem - rr * 21;
                const uint8_t* pb = p2 + (size_t)bb * 36 * 441;
                int yy = rr + kyl - 3, xx = cl + kxl - 3;
                bool inb = (lane < 49) && yy >= 0 && yy < 21 && xx >= 0 && xx < 21;
                int poff = yy * 21 + xx;
                float accv = 0.f;
                for (int c = 0; c < 36; c++) {
                    float wv = 0.f, v = 0.f;
                    if (lane < 49) wv = w3[c * 49 + lane];
                    if (inb) v = (float)pb[c * 441 + poff];
                    accv = fmaf(v, wv, accv);
                }
#pragma unroll
                for (int off = 32; off; off >>= 1) accv += __shfl_xor(accv, off, 64);
                float memv3 = m3r[rep] + accv;
                bool s = memv3 >= THR;
                if (lane == 0) out[(size_t)tl * 3528 + o] = s ? 1.f : 0.f;
            }
        }
    }
}

extern "C" void kernel_launch(void* const* d_in, const int* in_sizes, int n_in,
                              void* d_out, int out_size, void* d_ws, size_t ws_size,
                              hipStream_t stream) {
    const float* x  = (const float*)d_in[0];
    const float* w1 = (const float*)d_in[1];
    const float* w2 = (const float*)d_in[2];
    const float* w3 = (const float*)d_in[3];
    float* out = (float*)d_out;
    uint8_t* s1 = (uint8_t*)d_ws;
    uint8_t* p2 = (uint8_t*)d_ws + OFF_P2;
    uint32_t* bar = (uint32_t*)((char*)d_ws + OFF_BAR);

    zero_bar<<<1, 256, 0, stream>>>(bar);

    void* args[] = {(void*)&x, (void*)&w1, (void*)&w2, (void*)&w3,
                    (void*)&out, (void*)&s1, (void*)&p2, (void*)&bar};
    hipLaunchCooperativeKernel((void*)spike_persist, dim3(512), dim3(256),
                               args, 0, stream);
}

// Round 4
// 947.383 us; speedup vs baseline: 2.9370x; 1.7449x over previous
//
#include <hip/hip_runtime.h>
#include <stdint.h>

#define THR 10.0f
#define AGT __HIP_MEMORY_SCOPE_AGENT

// ---- workspace layout (bytes) ----
// s1 x2 (u8): 2 * 2,097,152 at 0          (double-buffered, t&1)
// p2 x2 (u8): 2 * 131,072  at 4,194,304
// barrier   : u32[288]     at 4,456,448
static constexpr size_t OFF_P2  = 4194304;
static constexpr size_t OFF_BAR = 4456448;

static __device__ __forceinline__ uint32_t ldu32(const uint32_t* p) {
    return __hip_atomic_load(p, __ATOMIC_RELAXED, AGT);
}
static __device__ __forceinline__ uint8_t ldu8(const uint8_t* p) {
    return __hip_atomic_load(p, __ATOMIC_RELAXED, AGT);
}
static __device__ __forceinline__ void stu16(uint16_t* p, uint16_t v) {
    __hip_atomic_store(p, v, __ATOMIC_RELAXED, AGT);
}
static __device__ __forceinline__ void stu8(uint8_t* p, uint8_t v) {
    __hip_atomic_store(p, v, __ATOMIC_RELAXED, AGT);
}

__global__ __launch_bounds__(256) void zero_bar(uint32_t* __restrict__ bar) {
    for (int i = threadIdx.x; i < 288; i += 256) bar[i] = 0u;
}

// Fence-free tree barrier, monotonic counters. All cross-block data moves via
// sc1 (agent-scope) accesses, so no L2 writeback/invalidate is required here.
// bar[g*16], g=0..7 : arrival counters (64 blocks each), 64B apart
// bar[128] : root (8 arrivals)   bar[144] : epoch   bar[160+g*16] : go lines
__device__ __forceinline__ void gbar(uint32_t* bar, int bid, uint32_t n) {
    __syncthreads();                       // drains vmcnt: block's sc1 stores visible
    if (threadIdx.x == 0) {
        const int g = bid >> 6;
        uint32_t a = __hip_atomic_fetch_add(bar + g * 16, 1u, __ATOMIC_RELAXED, AGT);
        if (a == 64u * n - 1u) {           // group closer
            uint32_t r = __hip_atomic_fetch_add(bar + 128, 1u, __ATOMIC_RELAXED, AGT);
            if (r == 8u * n - 1u)          // root closer
                __hip_atomic_fetch_add(bar + 144, 1u, __ATOMIC_RELAXED, AGT);
            while (__hip_atomic_load(bar + 144, __ATOMIC_RELAXED, AGT) < n)
                __builtin_amdgcn_s_sleep(4);
            __hip_atomic_fetch_add(bar + 160 + g * 16, 1u, __ATOMIC_RELAXED, AGT);
        } else {
            while (__hip_atomic_load(bar + 160 + g * 16, __ATOMIC_RELAXED, AGT) < n)
                __builtin_amdgcn_s_sleep(4);
        }
    }
    __syncthreads();
}

// Persistent kernel, 512 blocks x 256 threads, 2 blocks/CU.
// Pipeline: superstep k = A(t=k) + L3(t=k-2) + B(t=k-1); 21 barriers total.
// m1 in regs (16 f/thread), m2 in regs of blocks 0..287, m3 in 2 regs/wave.
__global__ __launch_bounds__(256, 2) void spike_persist(
    const float* __restrict__ x,    // (20,8,1,256,256)
    const float* __restrict__ w1,   // (4,1,5,5)
    const float* __restrict__ w2,   // (36,4,5,5)
    const float* __restrict__ w3,   // (1,36,7,7)
    float* __restrict__ out,        // (20,8,1,21,21)
    uint8_t* __restrict__ s1b,      // 2 buffers
    uint8_t* __restrict__ p2b,      // 2 buffers
    uint32_t* __restrict__ bar)
{
    __shared__ union {
        float   xs[2112];            // phase A: 8 x 264 input rows (halo 2)
        uint8_t sraw[4 * 73 * 76];   // phase B: raw s1 region (73 rows x 76B x 4ch)
    } u;
    __shared__ float ps[576];        // 4 x 12 x 12 pooled p1 tile (halo 2)
    __shared__ float mem_s[2304];    // 36 ch x 64 px
    __shared__ float bm_s[576];      // 36 ch x 16 blocks
    __shared__ int   wc_s[64];

    const int tid = threadIdx.x;
    const int bid = blockIdx.x;
    uint32_t nbar = 0;

    // ---- L1 ownership: 512 blocks = 8 b x 64 row-strips (4 rows each)
    const int b1 = bid >> 6;
    const int r0 = (bid & 63) * 4;
    const int tr = tid >> 7, tc = tid & 127;
    const int py = r0 + 2 * tr;
    const int px = 2 * tc;

    // ---- L2 ownership: blocks 0..287 = 8 b x (6x6) tiles of 8x8 px
    const bool l2act = bid < 288;
    const int b2 = bid / 36;
    const int ty2 = (bid % 36) / 6, tx2 = bid % 6;
    const int oy2 = ty2 * 8, ox2 = tx2 * 8;
    const int wave = tid >> 6, lane = tid & 63;
    const int pr = lane >> 3, pc = lane & 7;
    const int gy2 = oy2 + pr, gx2 = ox2 + pc;
    const bool valid2 = (gy2 < 42) && (gx2 < 42);

    // ---- L3 ownership: wave id, outputs wid and wid+2048 (<3528)
    const int wid = bid * 4 + wave;
    const int kyl = lane / 7, kxl = lane % 7;

    float m1r[4][2][2];
#pragma unroll
    for (int c = 0; c < 4; c++)
#pragma unroll
        for (int dy = 0; dy < 2; dy++)
#pragma unroll
            for (int dx = 0; dx < 2; dx++) m1r[c][dy][dx] = 0.f;
    float m2r[9];
#pragma unroll
    for (int i = 0; i < 9; i++) m2r[i] = 0.f;
    float m3r[2] = {0.f, 0.f};

    for (int k = 0; k < 22; k++) {
        // ================= A(t=k) =================
        if (k < 20) {
            const int t = k;
            uint8_t* s1w = s1b + (size_t)(t & 1) * 2097152;
            const float* xb = x + ((size_t)t * 8 + b1) * 65536;
            for (int idx = tid; idx < 2112; idx += 256) {
                int row = idx / 264, col = idx - row * 264;
                int gy = r0 + row - 2, gx = col - 2;
                float v = 0.f;
                if (gy >= 0 && gy < 256 && gx >= 0 && gx < 256) v = xb[gy * 256 + gx];
                u.xs[idx] = v;
            }
            __syncthreads();

            float p[6][6];
#pragma unroll
            for (int i = 0; i < 6; i++)
#pragma unroll
                for (int j = 0; j < 6; j++)
                    p[i][j] = u.xs[(2 * tr + i) * 264 + 2 * tc + j];

            float acc[4][2][2];
#pragma unroll
            for (int c = 0; c < 4; c++)
#pragma unroll
                for (int dy = 0; dy < 2; dy++)
#pragma unroll
                    for (int dx = 0; dx < 2; dx++) acc[c][dy][dx] = 0.f;
#pragma unroll
            for (int c = 0; c < 4; c++)
#pragma unroll
                for (int ky = 0; ky < 5; ky++)
#pragma unroll
                    for (int kx = 0; kx < 5; kx++) {
                        float w = w1[c * 25 + ky * 5 + kx];
#pragma unroll
                        for (int dy = 0; dy < 2; dy++)
#pragma unroll
                            for (int dx = 0; dx < 2; dx++)
                                acc[c][dy][dx] = fmaf(p[dy + ky][dx + kx], w, acc[c][dy][dx]);
                    }

            float mem[4][2][2];
#pragma unroll
            for (int c = 0; c < 4; c++)
#pragma unroll
                for (int dy = 0; dy < 2; dy++)
#pragma unroll
                    for (int dx = 0; dx < 2; dx++)
                        mem[c][dy][dx] = m1r[c][dy][dx] + acc[c][dy][dx];

            int wc[2][2];
#pragma unroll
            for (int dy = 0; dy < 2; dy++)
#pragma unroll
                for (int dx = 0; dx < 2; dx++) {
                    int w = 0; float mx = mem[0][dy][dx];
#pragma unroll
                    for (int c = 1; c < 4; c++) {
                        float v = mem[c][dy][dx];
                        if (v > mx) { mx = v; w = c; }
                    }
                    wc[dy][dx] = w;
                }

            float bm[4];
#pragma unroll
            for (int c = 0; c < 4; c++)
                bm[c] = fmaxf(fmaxf(mem[c][0][0], mem[c][0][1]), fmaxf(mem[c][1][0], mem[c][1][1]));

#pragma unroll
            for (int c = 0; c < 4; c++) {
                size_t base = ((size_t)(b1 * 4 + c)) * 65536 + (size_t)py * 256 + px;
#pragma unroll
                for (int dy = 0; dy < 2; dy++) {
                    uint16_t sp01;
                    float m0 = mem[c][dy][0];
                    bool s0 = (m0 >= THR) && (wc[dy][0] == c) && (m0 >= bm[c]);
                    m1r[c][dy][0] = fmaxf((s0 ? 0.f : m0) - 9.0f, 0.f);
                    float m1v = mem[c][dy][1];
                    bool s1v = (m1v >= THR) && (wc[dy][1] == c) && (m1v >= bm[c]);
                    m1r[c][dy][1] = fmaxf((s1v ? 0.f : m1v) - 9.0f, 0.f);
                    sp01 = (uint16_t)((s0 ? 1 : 0) | ((s1v ? 1 : 0) << 8));
                    stu16(reinterpret_cast<uint16_t*>(s1w + base + (size_t)dy * 256), sp01);
                }
            }
        }

        // ================= L3(t=k-2) =================
        if (k >= 2) {
            const int tl = k - 2;
            const uint8_t* p2r = p2b + (size_t)(tl & 1) * 131072;
#pragma unroll
            for (int rep = 0; rep < 2; rep++) {
                int o = wid + rep * 2048;
                if (o < 3528) {
                    int bb = o / 441, rem = o - bb * 441;
                    int rr = rem / 21, cl = rem - rr * 21;
                    const uint8_t* pb = p2r + (size_t)bb * 36 * 441;
                    int yy = rr + kyl - 3, xx = cl + kxl - 3;
                    bool inb = (lane < 49) && yy >= 0 && yy < 21 && xx >= 0 && xx < 21;
                    int poff = yy * 21 + xx;
                    float accv = 0.f;
                    for (int c = 0; c < 36; c++) {
                        float wv = 0.f, v = 0.f;
                        if (lane < 49) wv = w3[c * 49 + lane];
                        if (inb) v = (float)ldu8(pb + c * 441 + poff);
                        accv = fmaf(v, wv, accv);
                    }
#pragma unroll
                    for (int off = 32; off; off >>= 1) accv += __shfl_xor(accv, off, 64);
                    float memv3 = m3r[rep] + accv;
                    bool s = memv3 >= THR;
                    if (lane == 0) out[(size_t)tl * 3528 + o] = s ? 1.f : 0.f;
                    m3r[rep] = fmaxf(s ? 0.f : memv3, 0.f);
                }
            }
        }

        // ================= B(t=k-1) =================
        if (k >= 1 && k <= 20 && l2act) {
            const int tb = k - 1;
            const uint8_t* s1r = s1b + (size_t)(tb & 1) * 2097152;
            uint8_t* p2w = p2b + (size_t)(tb & 1) * 131072;

            __syncthreads();   // xs no longer needed; reuse union as sraw
            // stage s1 region: 4 ch x 73 rows x 19 words, coalesced sc1 loads
            {
                const int ry0 = oy2 * 6 - 12;
                const int cx0 = ox2 * 6 - 12;        // word-aligned (div by 4)
                uint32_t* sw = reinterpret_cast<uint32_t*>(u.sraw);
                for (int idx = tid; idx < 5548; idx += 256) {
                    int ch = idx / 1387, rem = idx - ch * 1387;
                    int row = rem / 19, w = rem - row * 19;
                    int grow = ry0 + row;
                    int gcol = cx0 + 4 * w;
                    uint32_t v = 0;
                    if (grow >= 0 && grow < 256 && gcol >= 0 && gcol < 256)
                        v = ldu32(reinterpret_cast<const uint32_t*>(
                                s1r + ((size_t)(b2 * 4 + ch) * 256 + grow) * 256 + gcol));
                    sw[idx] = v;
                }
            }
            __syncthreads();

            // pool 7x7 stride 6 from LDS bytes -> ps
            for (int idx = tid; idx < 576; idx += 256) {
                int ic = idx / 144, rem = idx - ic * 144;
                int r = rem / 12, cc2 = rem - r * 12;
                int gy = oy2 + r - 2, gx = ox2 + cc2 - 2;
                float v = 0.f;
                if (gy >= 0 && gy < 42 && gx >= 0 && gx < 42) {
                    const uint8_t* rp = u.sraw + ic * 5548 + r * 6 * 76 + cc2 * 6;
                    int m = 0;
#pragma unroll
                    for (int dy = 0; dy < 7; dy++)
#pragma unroll
                        for (int dx = 0; dx < 7; dx++) {
                            int uv = rp[dy * 76 + dx];
                            m = uv > m ? uv : m;
                        }
                    v = (float)m;
                }
                ps[idx] = v;
            }
            __syncthreads();

            float pv[4][5][5];
#pragma unroll
            for (int ic = 0; ic < 4; ic++)
#pragma unroll
                for (int i = 0; i < 5; i++)
#pragma unroll
                    for (int j = 0; j < 5; j++)
                        pv[ic][i][j] = ps[ic * 144 + (pr + i) * 12 + (pc + j)];

            float memv[9];
            for (int cc = 0; cc < 9; cc++) {
                int c = cc * 4 + wave;                       // wave-uniform
                const float* wr = w2 + (size_t)__builtin_amdgcn_readfirstlane(c) * 100;
                float accv = 0.f;
#pragma unroll
                for (int ic = 0; ic < 4; ic++)
#pragma unroll
                    for (int i = 0; i < 5; i++)
#pragma unroll
                        for (int j = 0; j < 5; j++)
                            accv = fmaf(pv[ic][i][j], wr[ic * 25 + i * 5 + j], accv);
                float m = valid2 ? (m2r[cc] + accv) : -1e30f;
                memv[cc] = m;
                mem_s[c * 64 + lane] = m;
            }
            __syncthreads();

            if (tid < 64) {
                float mx = mem_s[tid]; int w = 0;
                for (int c = 1; c < 36; c++) {
                    float v = mem_s[c * 64 + tid];
                    if (v > mx) { mx = v; w = c; }
                }
                wc_s[tid] = w;
            }
            for (int idx = tid; idx < 576; idx += 256) {
                int c = idx >> 4, blk = idx & 15;
                int l0 = (blk >> 2) * 16 + (blk & 3) * 2;
                float a = mem_s[c * 64 + l0],     bb2 = mem_s[c * 64 + l0 + 1];
                float d = mem_s[c * 64 + l0 + 8], e   = mem_s[c * 64 + l0 + 9];
                bm_s[idx] = fmaxf(fmaxf(a, bb2), fmaxf(d, e));
            }
            __syncthreads();

            const int blkl = (pr >> 1) * 4 + (pc >> 1);
            for (int cc = 0; cc < 9; cc++) {
                int c = cc * 4 + wave;
                if (valid2) {
                    float m = memv[cc];
                    bool s = (m >= THR) && (wc_s[lane] == c) && (m >= bm_s[c * 16 + blkl]);
                    m2r[cc] = fmaxf((s ? 0.f : m) - 1.0f, 0.f);
                }
            }

            for (int idx = tid; idx < 576; idx += 256) {
                int c = idx >> 4, blk = idx & 15;
                int br = blk >> 2, bc2 = blk & 3;
                int l0 = br * 16 + bc2 * 2;
                float bmv = bm_s[idx];
                uint8_t any = 0;
#pragma unroll
                for (int kk = 0; kk < 4; kk++) {
                    int dy = kk >> 1, dx = kk & 1;
                    int l = l0 + dy * 8 + dx;
                    int py2 = oy2 + 2 * br + dy, px2 = ox2 + 2 * bc2 + dx;
                    if (py2 < 42 && px2 < 42) {
                        float m = mem_s[c * 64 + l];
                        bool s = (m >= THR) && (wc_s[l] == c) && (m >= bmv);
                        any |= (uint8_t)s;
                    }
                }
                int gby = (oy2 >> 1) + br, gbx = (ox2 >> 1) + bc2;
                if (gby < 21 && gbx < 21)
                    stu8(p2w + ((size_t)(b2 * 36 + c) * 21 + gby) * 21 + gbx, any);
            }
        }

        if (k < 21) gbar(bar, bid, ++nbar);
    }
}

extern "C" void kernel_launch(void* const* d_in, const int* in_sizes, int n_in,
                              void* d_out, int out_size, void* d_ws, size_t ws_size,
                              hipStream_t stream) {
    const float* x  = (const float*)d_in[0];
    const float* w1 = (const float*)d_in[1];
    const float* w2 = (const float*)d_in[2];
    const float* w3 = (const float*)d_in[3];
    float* out = (float*)d_out;
    uint8_t* s1 = (uint8_t*)d_ws;
    uint8_t* p2 = (uint8_t*)d_ws + OFF_P2;
    uint32_t* bar = (uint32_t*)((char*)d_ws + OFF_BAR);

    zero_bar<<<1, 256, 0, stream>>>(bar);

    void* args[] = {(void*)&x, (void*)&w1, (void*)&w2, (void*)&w3,
                    (void*)&out, (void*)&s1, (void*)&p2, (void*)&bar};
    hipLaunchCooperativeKernel((void*)spike_persist, dim3(512), dim3(256),
                               args, 0, stream);
}

// Round 5
// 894.632 us; speedup vs baseline: 3.1102x; 1.0590x over previous
//
#include <hip/hip_runtime.h>
#include <stdint.h>

#define THR 10.0f
#define AGT __HIP_MEMORY_SCOPE_AGENT

// ---- workspace layout (bytes) ----
// s1 x2 (u8): 2 * 2,097,152 at 0          (double-buffered, t&1)
// p2 x2 (u8): 2 * 131,072  at 4,194,304
// barrier   : u32[288]     at 4,456,448
static constexpr size_t OFF_P2  = 4194304;
static constexpr size_t OFF_BAR = 4456448;

static __device__ __forceinline__ uint32_t ldu32(const uint32_t* p) {
    return __hip_atomic_load(p, __ATOMIC_RELAXED, AGT);
}
static __device__ __forceinline__ uint8_t ldu8(const uint8_t* p) {
    return __hip_atomic_load(p, __ATOMIC_RELAXED, AGT);
}
static __device__ __forceinline__ void stu16(uint16_t* p, uint16_t v) {
    __hip_atomic_store(p, v, __ATOMIC_RELAXED, AGT);
}
static __device__ __forceinline__ void stu8(uint8_t* p, uint8_t v) {
    __hip_atomic_store(p, v, __ATOMIC_RELAXED, AGT);
}

__global__ __launch_bounds__(256) void zero_bar(uint32_t* __restrict__ bar) {
    for (int i = threadIdx.x; i < 288; i += 256) bar[i] = 0u;
}

// Fence-free tree barrier, monotonic counters (all cross-block data moves via
// agent-scope accesses, so no L2 writeback/invalidate needed).
__device__ __forceinline__ void gbar(uint32_t* bar, int bid, uint32_t n) {
    __syncthreads();                       // drains vmcnt: block's sc1 stores done
    if (threadIdx.x == 0) {
        const int g = bid >> 6;
        uint32_t a = __hip_atomic_fetch_add(bar + g * 16, 1u, __ATOMIC_RELAXED, AGT);
        if (a == 64u * n - 1u) {           // group closer
            uint32_t r = __hip_atomic_fetch_add(bar + 128, 1u, __ATOMIC_RELAXED, AGT);
            if (r == 8u * n - 1u)          // root closer
                __hip_atomic_fetch_add(bar + 144, 1u, __ATOMIC_RELAXED, AGT);
            while (__hip_atomic_load(bar + 144, __ATOMIC_RELAXED, AGT) < n)
                __builtin_amdgcn_s_sleep(2);
            __hip_atomic_fetch_add(bar + 160 + g * 16, 1u, __ATOMIC_RELAXED, AGT);
        } else {
            while (__hip_atomic_load(bar + 160 + g * 16, __ATOMIC_RELAXED, AGT) < n)
                __builtin_amdgcn_s_sleep(2);
        }
    }
    __syncthreads();
}

// Persistent kernel, 512 blocks x 256 threads, 2 blocks/CU.
// Superstep k = A(t=k) + L3(t=k-2) + B(t=k-1); 21 barriers total.
// Layer2 re-tiled into 512 tiles (1 per block -> 1 B-tile per CU slot):
// per batch, 8x8 grid with even-aligned splits sizes {6,6,6,6,6,4,4,4}.
__global__ __launch_bounds__(256, 2) void spike_persist(
    const float* __restrict__ x,    // (20,8,1,256,256)
    const float* __restrict__ w1,   // (4,1,5,5)
    const float* __restrict__ w2,   // (36,4,5,5)
    const float* __restrict__ w3,   // (1,36,7,7)
    float* __restrict__ out,        // (20,8,1,21,21)
    uint8_t* __restrict__ s1b,      // 2 buffers
    uint8_t* __restrict__ p2b,      // 2 buffers
    uint32_t* __restrict__ bar)
{
    __shared__ union {
        float   xs[2112];            // phase A: 8 x 264 input rows (halo 2)
        uint8_t sraw[15616];         // phase B: s1 region 4ch x 61 rows x 64B
    } u;
    __shared__ float ps[400];        // 4 x 10 x 10 pooled p1 tile (halo 2)
    __shared__ float mem_s[1296];    // 36 ch x 36 planes (pitch 6)
    __shared__ float bm_s[324];      // 36 ch x 9 blocks (pitch 3)
    __shared__ int   wc_s[36];

    const int tid = threadIdx.x;
    const int bid = blockIdx.x;
    uint32_t nbar = 0;

    // ---- L1 ownership: 512 blocks = 8 b x 64 row-strips (4 rows each)
    const int b1 = bid >> 6;
    const int r0 = (bid & 63) * 4;
    const int tr = tid >> 7, tc = tid & 127;
    const int py = r0 + 2 * tr;
    const int px = 2 * tc;

    // ---- L2 ownership: 512 blocks = 8 b x 64 tiles (8x8, uneven splits)
    const int tIdx = bid & 63;
    const int b2 = bid >> 6;
    const int tyi = tIdx >> 3, txi = tIdx & 7;
    const int oy2 = tyi < 5 ? 6 * tyi : 30 + 4 * (tyi - 5);
    const int ox2 = txi < 5 ? 6 * txi : 30 + 4 * (txi - 5);
    const int th2 = tyi < 5 ? 6 : 4;
    const int tw2 = txi < 5 ? 6 : 4;
    const int wave = tid >> 6, lane = tid & 63;
    const int pr = lane / 6, pc = lane - 6 * pr;     // plane == lane for lane<36
    const bool act = (pr < th2) && (pc < tw2);       // tiles exactly cover 42x42
    const int prA = pr > 5 ? 0 : pr, pcA = pc;       // clamped LDS addressing

    // ---- L3 ownership: wave id, outputs wid and wid+2048 (<3528)
    const int wid = bid * 4 + wave;
    const int kyl = lane / 7, kxl = lane % 7;

    float m1r[4][2][2];
#pragma unroll
    for (int c = 0; c < 4; c++)
#pragma unroll
        for (int dy = 0; dy < 2; dy++)
#pragma unroll
            for (int dx = 0; dx < 2; dx++) m1r[c][dy][dx] = 0.f;
    float m2r[9];
#pragma unroll
    for (int i = 0; i < 9; i++) m2r[i] = 0.f;
    float m3r[2] = {0.f, 0.f};

    for (int k = 0; k < 22; k++) {
        // ================= A(t=k) =================
        if (k < 20) {
            const int t = k;
            uint8_t* s1w = s1b + (size_t)(t & 1) * 2097152;
            const float* xb = x + ((size_t)t * 8 + b1) * 65536;
            for (int idx = tid; idx < 2112; idx += 256) {
                int row = idx / 264, col = idx - row * 264;
                int gy = r0 + row - 2, gx = col - 2;
                float v = 0.f;
                if (gy >= 0 && gy < 256 && gx >= 0 && gx < 256) v = xb[gy * 256 + gx];
                u.xs[idx] = v;
            }
            __syncthreads();

            float p[6][6];
#pragma unroll
            for (int i = 0; i < 6; i++)
#pragma unroll
                for (int j = 0; j < 6; j++)
                    p[i][j] = u.xs[(2 * tr + i) * 264 + 2 * tc + j];

            float acc[4][2][2];
#pragma unroll
            for (int c = 0; c < 4; c++)
#pragma unroll
                for (int dy = 0; dy < 2; dy++)
#pragma unroll
                    for (int dx = 0; dx < 2; dx++) acc[c][dy][dx] = 0.f;
#pragma unroll
            for (int c = 0; c < 4; c++)
#pragma unroll
                for (int ky = 0; ky < 5; ky++)
#pragma unroll
                    for (int kx = 0; kx < 5; kx++) {
                        float w = w1[c * 25 + ky * 5 + kx];
#pragma unroll
                        for (int dy = 0; dy < 2; dy++)
#pragma unroll
                            for (int dx = 0; dx < 2; dx++)
                                acc[c][dy][dx] = fmaf(p[dy + ky][dx + kx], w, acc[c][dy][dx]);
                    }

            float mem[4][2][2];
#pragma unroll
            for (int c = 0; c < 4; c++)
#pragma unroll
                for (int dy = 0; dy < 2; dy++)
#pragma unroll
                    for (int dx = 0; dx < 2; dx++)
                        mem[c][dy][dx] = m1r[c][dy][dx] + acc[c][dy][dx];

            int wc[2][2];
#pragma unroll
            for (int dy = 0; dy < 2; dy++)
#pragma unroll
                for (int dx = 0; dx < 2; dx++) {
                    int w = 0; float mx = mem[0][dy][dx];
#pragma unroll
                    for (int c = 1; c < 4; c++) {
                        float v = mem[c][dy][dx];
                        if (v > mx) { mx = v; w = c; }
                    }
                    wc[dy][dx] = w;
                }

            float bm[4];
#pragma unroll
            for (int c = 0; c < 4; c++)
                bm[c] = fmaxf(fmaxf(mem[c][0][0], mem[c][0][1]), fmaxf(mem[c][1][0], mem[c][1][1]));

#pragma unroll
            for (int c = 0; c < 4; c++) {
                size_t base = ((size_t)(b1 * 4 + c)) * 65536 + (size_t)py * 256 + px;
#pragma unroll
                for (int dy = 0; dy < 2; dy++) {
                    float m0 = mem[c][dy][0];
                    bool s0 = (m0 >= THR) && (wc[dy][0] == c) && (m0 >= bm[c]);
                    m1r[c][dy][0] = fmaxf((s0 ? 0.f : m0) - 9.0f, 0.f);
                    float m1v = mem[c][dy][1];
                    bool s1v = (m1v >= THR) && (wc[dy][1] == c) && (m1v >= bm[c]);
                    m1r[c][dy][1] = fmaxf((s1v ? 0.f : m1v) - 9.0f, 0.f);
                    uint16_t sp01 = (uint16_t)((s0 ? 1 : 0) | ((s1v ? 1 : 0) << 8));
                    stu16(reinterpret_cast<uint16_t*>(s1w + base + (size_t)dy * 256), sp01);
                }
            }
        }

        // ================= L3(t=k-2) =================
        if (k >= 2) {
            const int tl = k - 2;
            const uint8_t* p2r = p2b + (size_t)(tl & 1) * 131072;
#pragma unroll
            for (int rep = 0; rep < 2; rep++) {
                int o = wid + rep * 2048;
                if (o < 3528) {
                    int bb = o / 441, rem = o - bb * 441;
                    int rr = rem / 21, cl = rem - rr * 21;
                    const uint8_t* pb = p2r + (size_t)bb * 36 * 441;
                    int yy = rr + kyl - 3, xx = cl + kxl - 3;
                    bool inb = (lane < 49) && yy >= 0 && yy < 21 && xx >= 0 && xx < 21;
                    int poff = yy * 21 + xx;
                    float accv = 0.f;
                    for (int c = 0; c < 36; c++) {
                        float wv = 0.f, v = 0.f;
                        if (lane < 49) wv = w3[c * 49 + lane];
                        if (inb) v = (float)ldu8(pb + c * 441 + poff);
                        accv = fmaf(v, wv, accv);
                    }
#pragma unroll
                    for (int off = 32; off; off >>= 1) accv += __shfl_xor(accv, off, 64);
                    float memv3 = m3r[rep] + accv;
                    bool s = memv3 >= THR;
                    if (lane == 0) out[(size_t)tl * 3528 + o] = s ? 1.f : 0.f;
                    m3r[rep] = fmaxf(s ? 0.f : memv3, 0.f);
                }
            }
        }

        // ================= B(t=k-1) =================
        if (k >= 1 && k <= 20) {
            const int tb = k - 1;
            const uint8_t* s1r = s1b + (size_t)(tb & 1) * 2097152;
            uint8_t* p2w = p2b + (size_t)(tb & 1) * 131072;

            __syncthreads();   // xs no longer needed; reuse union as sraw
            // stage s1 region: 4 ch x 61 rows x 16 words, coalesced sc1 loads
            {
                const int ry0 = oy2 * 6 - 12;
                const int cx0 = ox2 * 6 - 12;        // word-aligned
                uint32_t* sw = reinterpret_cast<uint32_t*>(u.sraw);
                for (int idx = tid; idx < 3904; idx += 256) {
                    int ch = idx / 976, rem = idx - ch * 976;
                    int row = rem >> 4, w = rem & 15;
                    int grow = ry0 + row;
                    int gcol = cx0 + 4 * w;
                    uint32_t v = 0;
                    if (grow >= 0 && grow < 256 && gcol >= 0 && gcol < 256)
                        v = ldu32(reinterpret_cast<const uint32_t*>(
                                s1r + ((size_t)(b2 * 4 + ch) * 256 + grow) * 256 + gcol));
                    sw[idx] = v;
                }
            }
            __syncthreads();

            // pool 7x7 stride 6 from LDS bytes -> ps (pitch 10)
            for (int idx = tid; idx < 400; idx += 256) {
                int ic = idx / 100, rem = idx - ic * 100;
                int r = rem / 10, cc2 = rem - 10 * r;
                float v = 0.f;
                if (r < th2 + 4 && cc2 < tw2 + 4) {
                    int gy = oy2 - 2 + r, gx = ox2 - 2 + cc2;
                    if (gy >= 0 && gy < 42 && gx >= 0 && gx < 42) {
                        const uint8_t* rp = u.sraw + ic * 3904 + (6 * r) * 64 + 6 * cc2;
                        int m = 0;
#pragma unroll
                        for (int dy = 0; dy < 7; dy++)
#pragma unroll
                            for (int dx = 0; dx < 7; dx++) {
                                int uv = rp[dy * 64 + dx];
                                m = uv > m ? uv : m;
                            }
                        v = (float)m;
                    }
                }
                ps[idx] = v;
            }
            __syncthreads();

            float pv[4][5][5];
#pragma unroll
            for (int ic = 0; ic < 4; ic++)
#pragma unroll
                for (int i = 0; i < 5; i++)
#pragma unroll
                    for (int j = 0; j < 5; j++)
                        pv[ic][i][j] = ps[ic * 100 + (prA + i) * 10 + (pcA + j)];

            float memv[9];
            for (int cc = 0; cc < 9; cc++) {
                int c = cc * 4 + wave;                       // wave-uniform
                const float* wr = w2 + (size_t)__builtin_amdgcn_readfirstlane(c) * 100;
                float accv = 0.f;
#pragma unroll
                for (int ic = 0; ic < 4; ic++)
#pragma unroll
                    for (int i = 0; i < 5; i++)
#pragma unroll
                        for (int j = 0; j < 5; j++)
                            accv = fmaf(pv[ic][i][j], wr[ic * 25 + i * 5 + j], accv);
                float m = act ? (m2r[cc] + accv) : -1e30f;
                memv[cc] = m;
                if (lane < 36) mem_s[c * 36 + lane] = m;     // plane == lane
            }
            __syncthreads();

            if (tid < 36) {
                float mx = mem_s[tid]; int w = 0;
                for (int c = 1; c < 36; c++) {
                    float v = mem_s[c * 36 + tid];
                    if (v > mx) { mx = v; w = c; }
                }
                wc_s[tid] = w;
            }
            for (int idx = tid; idx < 324; idx += 256) {
                int c = idx / 9, blk = idx - 9 * c;
                int br = blk / 3, bc2 = blk - 3 * br;
                int l0 = 12 * br + 2 * bc2;
                float a = mem_s[c * 36 + l0],     bb2 = mem_s[c * 36 + l0 + 1];
                float d = mem_s[c * 36 + l0 + 6], e   = mem_s[c * 36 + l0 + 7];
                bm_s[idx] = fmaxf(fmaxf(a, bb2), fmaxf(d, e));
            }
            __syncthreads();

            const int blkl = (pr >> 1) * 3 + (pc >> 1);
            for (int cc = 0; cc < 9; cc++) {
                int c = cc * 4 + wave;
                if (act) {
                    float m = memv[cc];
                    bool s = (m >= THR) && (wc_s[lane] == c) && (m >= bm_s[c * 9 + blkl]);
                    m2r[cc] = fmaxf((s ? 0.f : m) - 1.0f, 0.f);
                }
            }

            for (int idx = tid; idx < 324; idx += 256) {
                int c = idx / 9, blk = idx - 9 * c;
                int br = blk / 3, bc2 = blk - 3 * br;
                if (2 * br < th2 && 2 * bc2 < tw2) {
                    int l0 = 12 * br + 2 * bc2;
                    float bmv = bm_s[idx];
                    uint8_t any = 0;
#pragma unroll
                    for (int kk = 0; kk < 4; kk++) {
                        int l = l0 + (kk >> 1) * 6 + (kk & 1);
                        float m = mem_s[c * 36 + l];
                        bool s = (m >= THR) && (wc_s[l] == c) && (m >= bmv);
                        any |= (uint8_t)s;
                    }
                    int gby = (oy2 >> 1) + br, gbx = (ox2 >> 1) + bc2;
                    stu8(p2w + ((size_t)(b2 * 36 + c) * 21 + gby) * 21 + gbx, any);
                }
            }
        }

        if (k < 21) gbar(bar, bid, ++nbar);
    }
}

extern "C" void kernel_launch(void* const* d_in, const int* in_sizes, int n_in,
                              void* d_out, int out_size, void* d_ws, size_t ws_size,
                              hipStream_t stream) {
    const float* x  = (const float*)d_in[0];
    const float* w1 = (const float*)d_in[1];
    const float* w2 = (const float*)d_in[2];
    const float* w3 = (const float*)d_in[3];
    float* out = (float*)d_out;
    uint8_t* s1 = (uint8_t*)d_ws;
    uint8_t* p2 = (uint8_t*)d_ws + OFF_P2;
    uint32_t* bar = (uint32_t*)((char*)d_ws + OFF_BAR);

    zero_bar<<<1, 256, 0, stream>>>(bar);

    void* args[] = {(void*)&x, (void*)&w1, (void*)&w2, (void*)&w3,
                    (void*)&out, (void*)&s1, (void*)&p2, (void*)&bar};
    hipLaunchCooperativeKernel((void*)spike_persist, dim3(512), dim3(256),
                               args, 0, stream);
}

// Round 6
// 856.556 us; speedup vs baseline: 3.2485x; 1.0445x over previous
//
#include <hip/hip_runtime.h>
#include <stdint.h>

#define THR 10.0f
#define AGT __HIP_MEMORY_SCOPE_AGENT

// ---- workspace layout (bytes) ----
// s1 x4 (u8): 4 * 2,097,152 = 8,388,608 at 0        (buffer t & 3)
// p2 x6 (u8): 6 * 131,072   =   786,432 at 8,388,608 (buffer t % 6)
// barrier   : u32[288]                  at 9,175,040
static constexpr size_t OFF_P2  = 8388608;
static constexpr size_t OFF_BAR = 9175040;

static __device__ __forceinline__ uint32_t ldu32(const uint32_t* p) {
    return __hip_atomic_load(p, __ATOMIC_RELAXED, AGT);
}
static __device__ __forceinline__ uint8_t ldu8(const uint8_t* p) {
    return __hip_atomic_load(p, __ATOMIC_RELAXED, AGT);
}
static __device__ __forceinline__ void stu16(uint16_t* p, uint16_t v) {
    __hip_atomic_store(p, v, __ATOMIC_RELAXED, AGT);
}
static __device__ __forceinline__ void stu8(uint8_t* p, uint8_t v) {
    __hip_atomic_store(p, v, __ATOMIC_RELAXED, AGT);
}
// Forced coherence-point read: RMW with 0 always executes at the MALL,
// immune to any stale-copy-in-local-cache pathology a plain load may have.
static __device__ __forceinline__ uint32_t rmwread(uint32_t* p) {
    return __hip_atomic_fetch_add(p, 0u, __ATOMIC_RELAXED, AGT);
}

__global__ __launch_bounds__(256) void zero_bar(uint32_t* __restrict__ bar) {
    for (int i = threadIdx.x; i < 288; i += 256) bar[i] = 0u;
}

// Fence-free tree barrier, monotonic counters; ALL waits poll via fetch_add(0).
__device__ __forceinline__ void gbar(uint32_t* bar, int bid, uint32_t n) {
    __syncthreads();                       // drains vmcnt: block's sc1 stores done
    if (threadIdx.x == 0) {
        const int g = bid >> 6;
        uint32_t a = __hip_atomic_fetch_add(bar + g * 16, 1u, __ATOMIC_RELAXED, AGT);
        if (a == 64u * n - 1u) {           // group closer
            uint32_t r = __hip_atomic_fetch_add(bar + 128, 1u, __ATOMIC_RELAXED, AGT);
            if (r == 8u * n - 1u)          // root closer
                __hip_atomic_fetch_add(bar + 144, 1u, __ATOMIC_RELAXED, AGT);
            while (rmwread(bar + 144) < n)
                __builtin_amdgcn_s_sleep(4);
            __hip_atomic_fetch_add(bar + 160 + g * 16, 1u, __ATOMIC_RELAXED, AGT);
        } else {
            while (rmwread(bar + 160 + g * 16) < n)
                __builtin_amdgcn_s_sleep(4);
        }
    }
    __syncthreads();
}

// Persistent kernel, 512 blocks x 256 threads, 2 blocks/CU.
// Superstep k (k=0..11): A(2k),A(2k+1) ; L3(2k-4),L3(2k-3) ; B(2k-2),B(2k-1).
// 11 barriers total. m1/m2/m3 state in registers (block-sequential in t).
__global__ __launch_bounds__(256, 2) void spike_persist(
    const float* __restrict__ x,    // (20,8,1,256,256)
    const float* __restrict__ w1,   // (4,1,5,5)
    const float* __restrict__ w2,   // (36,4,5,5)
    const float* __restrict__ w3,   // (1,36,7,7)
    float* __restrict__ out,        // (20,8,1,21,21)
    uint8_t* __restrict__ s1b,      // 4 buffers
    uint8_t* __restrict__ p2b,      // 6 buffers
    uint32_t* __restrict__ bar)
{
    __shared__ union {
        float   xs[2112];            // phase A: 8 x 264 input rows (halo 2)
        uint8_t sraw[15616];         // phase B: s1 region 4ch x 61 rows x 64B
    } u;
    __shared__ float ps[400];        // 4 x 10 x 10 pooled p1 tile (halo 2)
    __shared__ float mem_s[1296];    // 36 ch x 36 planes (pitch 6)
    __shared__ float bm_s[324];      // 36 ch x 9 blocks (pitch 3)
    __shared__ int   wc_s[36];

    const int tid = threadIdx.x;
    const int bid = blockIdx.x;
    uint32_t nbar = 0;

    // ---- L1 ownership: 512 blocks = 8 b x 64 row-strips (4 rows each)
    const int b1 = bid >> 6;
    const int r0 = (bid & 63) * 4;
    const int tr = tid >> 7, tc = tid & 127;
    const int py = r0 + 2 * tr;
    const int px = 2 * tc;

    // ---- L2 ownership: 512 blocks = 8 b x 64 tiles (8x8, uneven splits)
    const int tIdx = bid & 63;
    const int b2 = bid >> 6;
    const int tyi = tIdx >> 3, txi = tIdx & 7;
    const int oy2 = tyi < 5 ? 6 * tyi : 30 + 4 * (tyi - 5);
    const int ox2 = txi < 5 ? 6 * txi : 30 + 4 * (txi - 5);
    const int th2 = tyi < 5 ? 6 : 4;
    const int tw2 = txi < 5 ? 6 : 4;
    const int wave = tid >> 6, lane = tid & 63;
    const int pr = lane / 6, pc = lane - 6 * pr;     // plane == lane for lane<36
    const bool act = (pr < th2) && (pc < tw2);       // tiles exactly cover 42x42
    const int prA = pr > 5 ? 0 : pr, pcA = pc;       // clamped LDS addressing

    // ---- L3 ownership: wave id, outputs wid and wid+2048 (<3528)
    const int wid = bid * 4 + wave;
    const int kyl = lane / 7, kxl = lane % 7;

    float m1r[4][2][2];
#pragma unroll
    for (int c = 0; c < 4; c++)
#pragma unroll
        for (int dy = 0; dy < 2; dy++)
#pragma unroll
            for (int dx = 0; dx < 2; dx++) m1r[c][dy][dx] = 0.f;
    float m2r[9];
#pragma unroll
    for (int i = 0; i < 9; i++) m2r[i] = 0.f;
    float m3r[2] = {0.f, 0.f};

    for (int k = 0; k < 12; k++) {
        // ================= A(t=2k), A(t=2k+1) =================
        for (int tt = 0; tt < 2; tt++) {
            const int t = 2 * k + tt;
            if (t >= 20) break;
            uint8_t* s1w = s1b + (size_t)(t & 3) * 2097152;
            const float* xb = x + ((size_t)t * 8 + b1) * 65536;
            __syncthreads();               // prior xs readers done
            for (int idx = tid; idx < 2112; idx += 256) {
                int row = idx / 264, col = idx - row * 264;
                int gy = r0 + row - 2, gx = col - 2;
                float v = 0.f;
                if (gy >= 0 && gy < 256 && gx >= 0 && gx < 256) v = xb[gy * 256 + gx];
                u.xs[idx] = v;
            }
            __syncthreads();

            float p[6][6];
#pragma unroll
            for (int i = 0; i < 6; i++)
#pragma unroll
                for (int j = 0; j < 6; j++)
                    p[i][j] = u.xs[(2 * tr + i) * 264 + 2 * tc + j];

            float acc[4][2][2];
#pragma unroll
            for (int c = 0; c < 4; c++)
#pragma unroll
                for (int dy = 0; dy < 2; dy++)
#pragma unroll
                    for (int dx = 0; dx < 2; dx++) acc[c][dy][dx] = 0.f;
#pragma unroll
            for (int c = 0; c < 4; c++)
#pragma unroll
                for (int ky = 0; ky < 5; ky++)
#pragma unroll
                    for (int kx = 0; kx < 5; kx++) {
                        float w = w1[c * 25 + ky * 5 + kx];
#pragma unroll
                        for (int dy = 0; dy < 2; dy++)
#pragma unroll
                            for (int dx = 0; dx < 2; dx++)
                                acc[c][dy][dx] = fmaf(p[dy + ky][dx + kx], w, acc[c][dy][dx]);
                    }

            float mem[4][2][2];
#pragma unroll
            for (int c = 0; c < 4; c++)
#pragma unroll
                for (int dy = 0; dy < 2; dy++)
#pragma unroll
                    for (int dx = 0; dx < 2; dx++)
                        mem[c][dy][dx] = m1r[c][dy][dx] + acc[c][dy][dx];

            int wc[2][2];
#pragma unroll
            for (int dy = 0; dy < 2; dy++)
#pragma unroll
                for (int dx = 0; dx < 2; dx++) {
                    int w = 0; float mx = mem[0][dy][dx];
#pragma unroll
                    for (int c = 1; c < 4; c++) {
                        float v = mem[c][dy][dx];
                        if (v > mx) { mx = v; w = c; }
                    }
                    wc[dy][dx] = w;
                }

            float bm[4];
#pragma unroll
            for (int c = 0; c < 4; c++)
                bm[c] = fmaxf(fmaxf(mem[c][0][0], mem[c][0][1]), fmaxf(mem[c][1][0], mem[c][1][1]));

#pragma unroll
            for (int c = 0; c < 4; c++) {
                size_t base = ((size_t)(b1 * 4 + c)) * 65536 + (size_t)py * 256 + px;
#pragma unroll
                for (int dy = 0; dy < 2; dy++) {
                    float m0 = mem[c][dy][0];
                    bool s0 = (m0 >= THR) && (wc[dy][0] == c) && (m0 >= bm[c]);
                    m1r[c][dy][0] = fmaxf((s0 ? 0.f : m0) - 9.0f, 0.f);
                    float m1v = mem[c][dy][1];
                    bool s1v = (m1v >= THR) && (wc[dy][1] == c) && (m1v >= bm[c]);
                    m1r[c][dy][1] = fmaxf((s1v ? 0.f : m1v) - 9.0f, 0.f);
                    uint16_t sp01 = (uint16_t)((s0 ? 1 : 0) | ((s1v ? 1 : 0) << 8));
                    stu16(reinterpret_cast<uint16_t*>(s1w + base + (size_t)dy * 256), sp01);
                }
            }
        }

        // ================= L3(t=2k-4), L3(t=2k-3) =================
        for (int tt = 0; tt < 2; tt++) {
            const int tl = 2 * k - 4 + tt;
            if (tl < 0 || tl >= 20) continue;
            const uint8_t* p2r = p2b + (size_t)(tl % 6) * 131072;
#pragma unroll
            for (int rep = 0; rep < 2; rep++) {
                int o = wid + rep * 2048;
                if (o < 3528) {
                    int bb = o / 441, rem = o - bb * 441;
                    int rr = rem / 21, cl = rem - rr * 21;
                    const uint8_t* pb = p2r + (size_t)bb * 36 * 441;
                    int yy = rr + kyl - 3, xx = cl + kxl - 3;
                    bool inb = (lane < 49) && yy >= 0 && yy < 21 && xx >= 0 && xx < 21;
                    int poff = yy * 21 + xx;
                    float accv = 0.f;
                    for (int c = 0; c < 36; c++) {
                        float wv = 0.f, v = 0.f;
                        if (lane < 49) wv = w3[c * 49 + lane];
                        if (inb) v = (float)ldu8(pb + c * 441 + poff);
                        accv = fmaf(v, wv, accv);
                    }
#pragma unroll
                    for (int off = 32; off; off >>= 1) accv += __shfl_xor(accv, off, 64);
                    float memv3 = m3r[rep] + accv;
                    bool s = memv3 >= THR;
                    if (lane == 0) out[(size_t)tl * 3528 + o] = s ? 1.f : 0.f;
                    m3r[rep] = fmaxf(s ? 0.f : memv3, 0.f);
                }
            }
        }

        // ================= B(t=2k-2), B(t=2k-1) =================
        for (int tt = 0; tt < 2; tt++) {
            const int tb = 2 * k - 2 + tt;
            if (tb < 0 || tb >= 20) continue;
            const uint8_t* s1r = s1b + (size_t)(tb & 3) * 2097152;
            uint8_t* p2w = p2b + (size_t)(tb % 6) * 131072;

            __syncthreads();   // prior LDS readers done; reuse union as sraw
            {
                const int ry0 = oy2 * 6 - 12;
                const int cx0 = ox2 * 6 - 12;        // word-aligned
                uint32_t* sw = reinterpret_cast<uint32_t*>(u.sraw);
                for (int idx = tid; idx < 3904; idx += 256) {
                    int ch = idx / 976, rem = idx - ch * 976;
                    int row = rem >> 4, w = rem & 15;
                    int grow = ry0 + row;
                    int gcol = cx0 + 4 * w;
                    uint32_t v = 0;
                    if (grow >= 0 && grow < 256 && gcol >= 0 && gcol < 256)
                        v = ldu32(reinterpret_cast<const uint32_t*>(
                                s1r + ((size_t)(b2 * 4 + ch) * 256 + grow) * 256 + gcol));
                    sw[idx] = v;
                }
            }
            __syncthreads();

            // pool 7x7 stride 6 from LDS bytes -> ps (pitch 10)
            for (int idx = tid; idx < 400; idx += 256) {
                int ic = idx / 100, rem = idx - ic * 100;
                int r = rem / 10, cc2 = rem - 10 * r;
                float v = 0.f;
                if (r < th2 + 4 && cc2 < tw2 + 4) {
                    int gy = oy2 - 2 + r, gx = ox2 - 2 + cc2;
                    if (gy >= 0 && gy < 42 && gx >= 0 && gx < 42) {
                        const uint8_t* rp = u.sraw + ic * 3904 + (6 * r) * 64 + 6 * cc2;
                        int m = 0;
#pragma unroll
                        for (int dy = 0; dy < 7; dy++)
#pragma unroll
                            for (int dx = 0; dx < 7; dx++) {
                                int uv = rp[dy * 64 + dx];
                                m = uv > m ? uv : m;
                            }
                        v = (float)m;
                    }
                }
                ps[idx] = v;
            }
            __syncthreads();

            float pv[4][5][5];
#pragma unroll
            for (int ic = 0; ic < 4; ic++)
#pragma unroll
                for (int i = 0; i < 5; i++)
#pragma unroll
                    for (int j = 0; j < 5; j++)
                        pv[ic][i][j] = ps[ic * 100 + (prA + i) * 10 + (pcA + j)];

            float memv[9];
            for (int cc = 0; cc < 9; cc++) {
                int c = cc * 4 + wave;                       // wave-uniform
                const float* wr = w2 + (size_t)__builtin_amdgcn_readfirstlane(c) * 100;
                float accv = 0.f;
#pragma unroll
                for (int ic = 0; ic < 4; ic++)
#pragma unroll
                    for (int i = 0; i < 5; i++)
#pragma unroll
                        for (int j = 0; j < 5; j++)
                            accv = fmaf(pv[ic][i][j], wr[ic * 25 + i * 5 + j], accv);
                float m = act ? (m2r[cc] + accv) : -1e30f;
                memv[cc] = m;
                if (lane < 36) mem_s[c * 36 + lane] = m;     // plane == lane
            }
            __syncthreads();

            if (tid < 36) {
                float mx = mem_s[tid]; int w = 0;
                for (int c = 1; c < 36; c++) {
                    float v = mem_s[c * 36 + tid];
                    if (v > mx) { mx = v; w = c; }
                }
                wc_s[tid] = w;
            }
            for (int idx = tid; idx < 324; idx += 256) {
                int c = idx / 9, blk = idx - 9 * c;
                int br = blk / 3, bc2 = blk - 3 * br;
                int l0 = 12 * br + 2 * bc2;
                float a = mem_s[c * 36 + l0],     bb2 = mem_s[c * 36 + l0 + 1];
                float d = mem_s[c * 36 + l0 + 6], e   = mem_s[c * 36 + l0 + 7];
                bm_s[idx] = fmaxf(fmaxf(a, bb2), fmaxf(d, e));
            }
            __syncthreads();

            const int blkl = (pr >> 1) * 3 + (pc >> 1);
            for (int cc = 0; cc < 9; cc++) {
                int c = cc * 4 + wave;
                if (act) {
                    float m = memv[cc];
                    bool s = (m >= THR) && (wc_s[lane] == c) && (m >= bm_s[c * 9 + blkl]);
                    m2r[cc] = fmaxf((s ? 0.f : m) - 1.0f, 0.f);
                }
            }

            for (int idx = tid; idx < 324; idx += 256) {
                int c = idx / 9, blk = idx - 9 * c;
                int br = blk / 3, bc2 = blk - 3 * br;
                if (2 * br < th2 && 2 * bc2 < tw2) {
                    int l0 = 12 * br + 2 * bc2;
                    float bmv = bm_s[idx];
                    uint8_t any = 0;
#pragma unroll
                    for (int kk = 0; kk < 4; kk++) {
                        int l = l0 + (kk >> 1) * 6 + (kk & 1);
                        float m = mem_s[c * 36 + l];
                        bool s = (m >= THR) && (wc_s[l] == c) && (m >= bmv);
                        any |= (uint8_t)s;
                    }
                    int gby = (oy2 >> 1) + br, gbx = (ox2 >> 1) + bc2;
                    stu8(p2w + ((size_t)(b2 * 36 + c) * 21 + gby) * 21 + gbx, any);
                }
            }
        }

        if (k < 11) gbar(bar, bid, ++nbar);
    }
}

extern "C" void kernel_launch(void* const* d_in, const int* in_sizes, int n_in,
                              void* d_out, int out_size, void* d_ws, size_t ws_size,
                              hipStream_t stream) {
    const float* x  = (const float*)d_in[0];
    const float* w1 = (const float*)d_in[1];
    const float* w2 = (const float*)d_in[2];
    const float* w3 = (const float*)d_in[3];
    float* out = (float*)d_out;
    uint8_t* s1 = (uint8_t*)d_ws;
    uint8_t* p2 = (uint8_t*)d_ws + OFF_P2;
    uint32_t* bar = (uint32_t*)((char*)d_ws + OFF_BAR);

    zero_bar<<<1, 256, 0, stream>>>(bar);

    void* args[] = {(void*)&x, (void*)&w1, (void*)&w2, (void*)&w3,
                    (void*)&out, (void*)&s1, (void*)&p2, (void*)&bar};
    hipLaunchCooperativeKernel((void*)spike_persist, dim3(512), dim3(256),
                               args, 0, stream);
}

// Round 7
// 855.369 us; speedup vs baseline: 3.2530x; 1.0014x over previous
//
#include <hip/hip_runtime.h>
#include <stdint.h>

#define THR 10.0f
#define AGT __HIP_MEMORY_SCOPE_AGENT

// ---- workspace layout (bytes) ----
// s1 x4 (u8): 4 * 2,097,152 = 8,388,608 at 0        (buffer t & 3)
// p2 x6 (u8): 6 * 131,072   =   786,432 at 8,388,608 (buffer t % 6)
// barrier   : u32[256]                  at 9,175,040 (per-group, 32 u32 apart)
static constexpr size_t OFF_P2  = 8388608;
static constexpr size_t OFF_BAR = 9175040;

static __device__ __forceinline__ uint32_t ldu32(const uint32_t* p) {
    return __hip_atomic_load(p, __ATOMIC_RELAXED, AGT);
}
static __device__ __forceinline__ uint8_t ldu8(const uint8_t* p) {
    return __hip_atomic_load(p, __ATOMIC_RELAXED, AGT);
}
static __device__ __forceinline__ void stu16(uint16_t* p, uint16_t v) {
    __hip_atomic_store(p, v, __ATOMIC_RELAXED, AGT);
}
static __device__ __forceinline__ void stu8(uint8_t* p, uint8_t v) {
    __hip_atomic_store(p, v, __ATOMIC_RELAXED, AGT);
}
static __device__ __forceinline__ uint32_t rmwread(uint32_t* p) {
    return __hip_atomic_fetch_add(p, 0u, __ATOMIC_RELAXED, AGT);
}

__global__ __launch_bounds__(256) void zero_bar(uint32_t* __restrict__ bar) {
    if (threadIdx.x < 256) bar[threadIdx.x] = 0u;
}

// Group-local barrier (64 blocks of one batch group). All cross-block data
// flow is intra-group, so no global sync is ever needed.
// bar[g*32] : arrival counter ; bar[g*32+16] : go epoch (monotonic)
__device__ __forceinline__ void gbar(uint32_t* bar, int bid, uint32_t n) {
    __syncthreads();                       // drains vmcnt: block's sc1 stores done
    if (threadIdx.x == 0) {
        uint32_t* base = bar + (bid >> 6) * 32;
        uint32_t a = __hip_atomic_fetch_add(base, 1u, __ATOMIC_RELAXED, AGT);
        if (a == 64u * n - 1u)
            __hip_atomic_fetch_add(base + 16, 1u, __ATOMIC_RELAXED, AGT);
        while (rmwread(base + 16) < n)
            __builtin_amdgcn_s_sleep(1);
    }
    __syncthreads();
}

// Persistent kernel, 512 blocks x 256 threads, 2 blocks/CU.
// Superstep k (k=0..11): A(2k),A(2k+1) ; L3(2k-4),L3(2k-3) ; B(2k-2),B(2k-1).
// 11 group-local barriers. All latency chains force-unrolled for ILP.
__global__ __launch_bounds__(256, 2) void spike_persist(
    const float* __restrict__ x,    // (20,8,1,256,256)
    const float* __restrict__ w1,   // (4,1,5,5)
    const float* __restrict__ w2,   // (36,4,5,5)
    const float* __restrict__ w3,   // (1,36,7,7)
    float* __restrict__ out,        // (20,8,1,21,21)
    uint8_t* __restrict__ s1b,      // 4 buffers
    uint8_t* __restrict__ p2b,      // 6 buffers
    uint32_t* __restrict__ bar)
{
    __shared__ union {
        float   xs[2112];            // phase A: 8 x 264 input rows (halo 2)
        uint8_t sraw[15616];         // phase B: s1 region 4ch x 61 rows x 64B
    } u;
    __shared__ float ps[400];        // 4 x 10 x 10 pooled p1 tile (halo 2)
    __shared__ float mem_s[1296];    // 36 ch x 36 planes (pitch 6)
    __shared__ float bm_s[324];      // 36 ch x 9 blocks (pitch 3)
    __shared__ int   wc_s[36];

    const int tid = threadIdx.x;
    const int bid = blockIdx.x;
    uint32_t nbar = 0;

    // ---- L1 ownership: 512 blocks = 8 b x 64 row-strips (4 rows each)
    const int b1 = bid >> 6;
    const int r0 = (bid & 63) * 4;
    const int tr = tid >> 7, tc = tid & 127;
    const int py = r0 + 2 * tr;
    const int px = 2 * tc;

    // ---- L2 ownership: 512 blocks = 8 b x 64 tiles (8x8, uneven splits)
    const int tIdx = bid & 63;
    const int b2 = bid >> 6;
    const int tyi = tIdx >> 3, txi = tIdx & 7;
    const int oy2 = tyi < 5 ? 6 * tyi : 30 + 4 * (tyi - 5);
    const int ox2 = txi < 5 ? 6 * txi : 30 + 4 * (txi - 5);
    const int th2 = tyi < 5 ? 6 : 4;
    const int tw2 = txi < 5 ? 6 : 4;
    const int wave = tid >> 6, lane = tid & 63;
    const int pr = lane / 6, pc = lane - 6 * pr;     // plane == lane for lane<36
    const bool act = (pr < th2) && (pc < tw2);       // tiles exactly cover 42x42
    const int prA = pr > 5 ? 0 : pr, pcA = pc;       // clamped LDS addressing

    // ---- L3 ownership: group-local. lid3 in [0,256); outputs lid3, lid3+256
    const int lid3 = (bid & 63) * 4 + wave;
    const int kyl = lane / 7, kxl = lane % 7;

    // hoist w3 into registers (t-invariant)
    float w3v[36];
#pragma unroll
    for (int c = 0; c < 36; c++) w3v[c] = (lane < 49) ? w3[c * 49 + lane] : 0.f;

    float m1r[4][2][2];
#pragma unroll
    for (int c = 0; c < 4; c++)
#pragma unroll
        for (int dy = 0; dy < 2; dy++)
#pragma unroll
            for (int dx = 0; dx < 2; dx++) m1r[c][dy][dx] = 0.f;
    float m2r[9];
#pragma unroll
    for (int i = 0; i < 9; i++) m2r[i] = 0.f;
    float m3r[2] = {0.f, 0.f};

    for (int k = 0; k < 12; k++) {
        // ================= A(t=2k), A(t=2k+1) =================
        for (int tt = 0; tt < 2; tt++) {
            const int t = 2 * k + tt;
            if (t >= 20) break;
            uint8_t* s1w = s1b + (size_t)(t & 3) * 2097152;
            const float* xb = x + ((size_t)t * 8 + b1) * 65536;
            __syncthreads();               // prior xs readers done
#pragma unroll
            for (int i = 0; i < 9; i++) {
                int idx = tid + i * 256;
                if (idx < 2112) {
                    int row = idx / 264, col = idx - row * 264;
                    int gy = r0 + row - 2, gx = col - 2;
                    float v = 0.f;
                    if (gy >= 0 && gy < 256 && gx >= 0 && gx < 256) v = xb[gy * 256 + gx];
                    u.xs[idx] = v;
                }
            }
            __syncthreads();

            float p[6][6];
#pragma unroll
            for (int i = 0; i < 6; i++)
#pragma unroll
                for (int j = 0; j < 6; j++)
                    p[i][j] = u.xs[(2 * tr + i) * 264 + 2 * tc + j];

            float acc[4][2][2];
#pragma unroll
            for (int c = 0; c < 4; c++)
#pragma unroll
                for (int dy = 0; dy < 2; dy++)
#pragma unroll
                    for (int dx = 0; dx < 2; dx++) acc[c][dy][dx] = 0.f;
#pragma unroll
            for (int c = 0; c < 4; c++)
#pragma unroll
                for (int ky = 0; ky < 5; ky++)
#pragma unroll
                    for (int kx = 0; kx < 5; kx++) {
                        float w = w1[c * 25 + ky * 5 + kx];
#pragma unroll
                        for (int dy = 0; dy < 2; dy++)
#pragma unroll
                            for (int dx = 0; dx < 2; dx++)
                                acc[c][dy][dx] = fmaf(p[dy + ky][dx + kx], w, acc[c][dy][dx]);
                    }

            float mem[4][2][2];
#pragma unroll
            for (int c = 0; c < 4; c++)
#pragma unroll
                for (int dy = 0; dy < 2; dy++)
#pragma unroll
                    for (int dx = 0; dx < 2; dx++)
                        mem[c][dy][dx] = m1r[c][dy][dx] + acc[c][dy][dx];

            int wc[2][2];
#pragma unroll
            for (int dy = 0; dy < 2; dy++)
#pragma unroll
                for (int dx = 0; dx < 2; dx++) {
                    int w = 0; float mx = mem[0][dy][dx];
#pragma unroll
                    for (int c = 1; c < 4; c++) {
                        float v = mem[c][dy][dx];
                        if (v > mx) { mx = v; w = c; }
                    }
                    wc[dy][dx] = w;
                }

            float bm[4];
#pragma unroll
            for (int c = 0; c < 4; c++)
                bm[c] = fmaxf(fmaxf(mem[c][0][0], mem[c][0][1]), fmaxf(mem[c][1][0], mem[c][1][1]));

#pragma unroll
            for (int c = 0; c < 4; c++) {
                size_t base = ((size_t)(b1 * 4 + c)) * 65536 + (size_t)py * 256 + px;
#pragma unroll
                for (int dy = 0; dy < 2; dy++) {
                    float m0 = mem[c][dy][0];
                    bool s0 = (m0 >= THR) && (wc[dy][0] == c) && (m0 >= bm[c]);
                    m1r[c][dy][0] = fmaxf((s0 ? 0.f : m0) - 9.0f, 0.f);
                    float m1v = mem[c][dy][1];
                    bool s1v = (m1v >= THR) && (wc[dy][1] == c) && (m1v >= bm[c]);
                    m1r[c][dy][1] = fmaxf((s1v ? 0.f : m1v) - 9.0f, 0.f);
                    uint16_t sp01 = (uint16_t)((s0 ? 1 : 0) | ((s1v ? 1 : 0) << 8));
                    stu16(reinterpret_cast<uint16_t*>(s1w + base + (size_t)dy * 256), sp01);
                }
            }
        }

        // ================= L3(t=2k-4), L3(t=2k-3) : own batch only ========
        for (int tt = 0; tt < 2; tt++) {
            const int tl = 2 * k - 4 + tt;
            if (tl < 0 || tl >= 20) continue;
            const uint8_t* pb = p2b + (size_t)(tl % 6) * 131072 + (size_t)b2 * (36 * 441);
#pragma unroll
            for (int rep = 0; rep < 2; rep++) {
                int o = lid3 + rep * 256;
                if (o < 441) {
                    int rr = o / 21, cl = o - rr * 21;
                    int yy = rr + kyl - 3, xx = cl + kxl - 3;
                    bool inb = (lane < 49) && yy >= 0 && yy < 21 && xx >= 0 && xx < 21;
                    int poff = yy * 21 + xx;
                    float accv = 0.f;
#pragma unroll
                    for (int c = 0; c < 36; c++) {
                        float v = inb ? (float)ldu8(pb + c * 441 + poff) : 0.f;
                        accv = fmaf(v, w3v[c], accv);
                    }
#pragma unroll
                    for (int off = 32; off; off >>= 1) accv += __shfl_xor(accv, off, 64);
                    float memv3 = m3r[rep] + accv;
                    bool s = memv3 >= THR;
                    if (lane == 0) out[(size_t)tl * 3528 + b2 * 441 + o] = s ? 1.f : 0.f;
                    m3r[rep] = fmaxf(s ? 0.f : memv3, 0.f);
                }
            }
        }

        // ================= B(t=2k-2), B(t=2k-1) =================
        for (int tt = 0; tt < 2; tt++) {
            const int tb = 2 * k - 2 + tt;
            if (tb < 0 || tb >= 20) continue;
            const uint8_t* s1r = s1b + (size_t)(tb & 3) * 2097152;
            uint8_t* p2w = p2b + (size_t)(tb % 6) * 131072;

            __syncthreads();   // prior LDS readers done; reuse union as sraw
            {
                const int ry0 = oy2 * 6 - 12;
                const int cx0 = ox2 * 6 - 12;        // word-aligned
                uint32_t* sw = reinterpret_cast<uint32_t*>(u.sraw);
#pragma unroll
                for (int i = 0; i < 16; i++) {
                    int idx = tid + i * 256;
                    if (idx < 3904) {
                        int ch = idx / 976, rem = idx - ch * 976;
                        int row = rem >> 4, w = rem & 15;
                        int grow = ry0 + row;
                        int gcol = cx0 + 4 * w;
                        uint32_t v = 0;
                        if (grow >= 0 && grow < 256 && gcol >= 0 && gcol < 256)
                            v = ldu32(reinterpret_cast<const uint32_t*>(
                                    s1r + ((size_t)(b2 * 4 + ch) * 256 + grow) * 256 + gcol));
                        sw[idx] = v;
                    }
                }
            }
            __syncthreads();

            // pool 7x7 stride 6 from LDS bytes -> ps (pitch 10)
#pragma unroll
            for (int i = 0; i < 2; i++) {
                int idx = tid + i * 256;
                if (idx < 400) {
                    int ic = idx / 100, rem = idx - ic * 100;
                    int r = rem / 10, cc2 = rem - 10 * r;
                    float v = 0.f;
                    if (r < th2 + 4 && cc2 < tw2 + 4) {
                        int gy = oy2 - 2 + r, gx = ox2 - 2 + cc2;
                        if (gy >= 0 && gy < 42 && gx >= 0 && gx < 42) {
                            const uint8_t* rp = u.sraw + ic * 3904 + (6 * r) * 64 + 6 * cc2;
                            int m = 0;
#pragma unroll
                            for (int dy = 0; dy < 7; dy++)
#pragma unroll
                                for (int dx = 0; dx < 7; dx++) {
                                    int uv = rp[dy * 64 + dx];
                                    m = uv > m ? uv : m;
                                }
                            v = (float)m;
                        }
                    }
                    ps[idx] = v;
                }
            }
            __syncthreads();

            float pv[4][5][5];
#pragma unroll
            for (int ic = 0; ic < 4; ic++)
#pragma unroll
                for (int i = 0; i < 5; i++)
#pragma unroll
                    for (int j = 0; j < 5; j++)
                        pv[ic][i][j] = ps[ic * 100 + (prA + i) * 10 + (pcA + j)];

            float memv[9];
            for (int cc = 0; cc < 9; cc++) {
                int c = cc * 4 + wave;                       // wave-uniform
                const float* wr = w2 + (size_t)__builtin_amdgcn_readfirstlane(c) * 100;
                float accv = 0.f;
#pragma unroll
                for (int ic = 0; ic < 4; ic++)
#pragma unroll
                    for (int i = 0; i < 5; i++)
#pragma unroll
                        for (int j = 0; j < 5; j++)
                            accv = fmaf(pv[ic][i][j], wr[ic * 25 + i * 5 + j], accv);
                float m = act ? (m2r[cc] + accv) : -1e30f;
                memv[cc] = m;
                if (lane < 36) mem_s[c * 36 + lane] = m;     // plane == lane
            }
            __syncthreads();

            if (tid < 36) {
                float mx = mem_s[tid]; int w = 0;
#pragma unroll
                for (int c = 1; c < 36; c++) {
                    float v = mem_s[c * 36 + tid];
                    if (v > mx) { mx = v; w = c; }
                }
                wc_s[tid] = w;
            }
#pragma unroll
            for (int i = 0; i < 2; i++) {
                int idx = tid + i * 256;
                if (idx < 324) {
                    int c = idx / 9, blk = idx - 9 * c;
                    int br = blk / 3, bc2 = blk - 3 * br;
                    int l0 = 12 * br + 2 * bc2;
                    float a = mem_s[c * 36 + l0],     bb2 = mem_s[c * 36 + l0 + 1];
                    float d = mem_s[c * 36 + l0 + 6], e   = mem_s[c * 36 + l0 + 7];
                    bm_s[idx] = fmaxf(fmaxf(a, bb2), fmaxf(d, e));
                }
            }
            __syncthreads();

            const int blkl = (pr >> 1) * 3 + (pc >> 1);
            for (int cc = 0; cc < 9; cc++) {
                int c = cc * 4 + wave;
                if (act) {
                    float m = memv[cc];
                    bool s = (m >= THR) && (wc_s[lane] == c) && (m >= bm_s[c * 9 + blkl]);
                    m2r[cc] = fmaxf((s ? 0.f : m) - 1.0f, 0.f);
                }
            }

#pragma unroll
            for (int i = 0; i < 2; i++) {
                int idx = tid + i * 256;
                if (idx < 324) {
                    int c = idx / 9, blk = idx - 9 * c;
                    int br = blk / 3, bc2 = blk - 3 * br;
                    if (2 * br < th2 && 2 * bc2 < tw2) {
                        int l0 = 12 * br + 2 * bc2;
                        float bmv = bm_s[idx];
                        uint8_t any = 0;
#pragma unroll
                        for (int kk = 0; kk < 4; kk++) {
                            int l = l0 + (kk >> 1) * 6 + (kk & 1);
                            float m = mem_s[c * 36 + l];
                            bool s = (m >= THR) && (wc_s[l] == c) && (m >= bmv);
                            any |= (uint8_t)s;
                        }
                        int gby = (oy2 >> 1) + br, gbx = (ox2 >> 1) + bc2;
                        stu8(p2w + ((size_t)(b2 * 36 + c) * 21 + gby) * 21 + gbx, any);
                    }
                }
            }
        }

        if (k < 11) gbar(bar, bid, ++nbar);
    }
}

extern "C" void kernel_launch(void* const* d_in, const int* in_sizes, int n_in,
                              void* d_out, int out_size, void* d_ws, size_t ws_size,
                              hipStream_t stream) {
    const float* x  = (const float*)d_in[0];
    const float* w1 = (const float*)d_in[1];
    const float* w2 = (const float*)d_in[2];
    const float* w3 = (const float*)d_in[3];
    float* out = (float*)d_out;
    uint8_t* s1 = (uint8_t*)d_ws;
    uint8_t* p2 = (uint8_t*)d_ws + OFF_P2;
    uint32_t* bar = (uint32_t*)((char*)d_ws + OFF_BAR);

    zero_bar<<<1, 256, 0, stream>>>(bar);

    void* args[] = {(void*)&x, (void*)&w1, (void*)&w2, (void*)&w3,
                    (void*)&out, (void*)&s1, (void*)&p2, (void*)&bar};
    hipLaunchCooperativeKernel((void*)spike_persist, dim3(512), dim3(256),
                               args, 0, stream);
}

// Round 8
// 459.129 us; speedup vs baseline: 6.0604x; 1.8630x over previous
//
#include <hip/hip_runtime.h>
#include <stdint.h>

#define THR 10.0f
#define AGT __HIP_MEMORY_SCOPE_AGENT

// ---- workspace layout (bytes) ----
// s1m x4 (u16 bitmask per 2x2 block): 4 * 262,144 = 1,048,576 at 0   (t & 3)
// p2m x6 (2 u32 per cell, 36 ch bits): 6 * 32,768 =   196,608 at 1,048,576 (t % 6)
// barrier: u32[256] at 1,245,184
static constexpr size_t OFF_P2  = 1048576;
static constexpr size_t OFF_BAR = 1245184;

static __device__ __forceinline__ uint32_t ldu32(const uint32_t* p) {
    return __hip_atomic_load(p, __ATOMIC_RELAXED, AGT);
}
static __device__ __forceinline__ void stu32(uint32_t* p, uint32_t v) {
    __hip_atomic_store(p, v, __ATOMIC_RELAXED, AGT);
}
static __device__ __forceinline__ void stu16(uint16_t* p, uint16_t v) {
    __hip_atomic_store(p, v, __ATOMIC_RELAXED, AGT);
}
static __device__ __forceinline__ uint32_t rmwread(uint32_t* p) {
    return __hip_atomic_fetch_add(p, 0u, __ATOMIC_RELAXED, AGT);
}

__global__ __launch_bounds__(256) void zero_bar(uint32_t* __restrict__ bar) {
    if (threadIdx.x < 256) bar[threadIdx.x] = 0u;
}

// Group-local barrier (64 blocks of one batch group); all dataflow is
// intra-group. bar[g*32]: arrival counter; bar[g*32+16]: go epoch.
__device__ __forceinline__ void gbar(uint32_t* bar, int bid, uint32_t n) {
    __syncthreads();                       // drains vmcnt: sc1 stores done
    if (threadIdx.x == 0) {
        uint32_t* base = bar + (bid >> 6) * 32;
        uint32_t a = __hip_atomic_fetch_add(base, 1u, __ATOMIC_RELAXED, AGT);
        if (a == 64u * n - 1u)
            __hip_atomic_fetch_add(base + 16, 1u, __ATOMIC_RELAXED, AGT);
        while (rmwread(base + 16) < n)
            __builtin_amdgcn_s_sleep(2);
    }
    __syncthreads();
}

// Persistent kernel, 512 blocks x 256 threads, 2 blocks/CU.
// Superstep k: A(2k),A(2k+1) ; L3(2k-4),L3(2k-3) ; B(2k-2),B(2k-1).
// All cross-block tensors are bit-packed to minimize uncached transactions:
// s1: u16 per 2x2 spatial block (bit = c*4+dy*2+dx); p2: 36-bit mask per cell.
__global__ __launch_bounds__(256, 2) void spike_persist(
    const float* __restrict__ x,    // (20,8,1,256,256)
    const float* __restrict__ w1,   // (4,1,5,5)
    const float* __restrict__ w2,   // (36,4,5,5)
    const float* __restrict__ w3,   // (1,36,7,7)
    float* __restrict__ out,        // (20,8,1,21,21)
    uint8_t* __restrict__ s1b,      // 4 buffers of u16[8][128][128]
    uint8_t* __restrict__ p2b,      // 6 buffers of u32[8][441][2]
    uint32_t* __restrict__ bar)
{
    __shared__ union {
        float    xs[2112];           // phase A: 8 x 264 input rows (halo 2)
        uint32_t st32[527];          // phase B: staged s1m 31 rows x 17 u32
    } u;
    __shared__ float    ps[400];     // 4 x 10 x 10 pooled p1 tile (halo 2)
    __shared__ float    mem_s[1296]; // 36 ch x 36 planes (pitch 6)
    __shared__ float    bm_s[324];   // 36 ch x 9 blocks (pitch 3)
    __shared__ int      wc_s[36];
    __shared__ uint32_t p2a[18];     // 9 blocks x 2 words of channel bits

    const int tid = threadIdx.x;
    const int bid = blockIdx.x;
    uint32_t nbar = 0;

    // ---- L1 ownership: 512 blocks = 8 b x 64 row-strips (4 rows each)
    const int b1 = bid >> 6;
    const int r0 = (bid & 63) * 4;
    const int tr = tid >> 7, tc = tid & 127;
    const int py = r0 + 2 * tr;
    const int px = 2 * tc;

    // ---- L2 ownership: 512 blocks = 8 b x 64 tiles (8x8, uneven splits)
    const int tIdx = bid & 63;
    const int b2 = bid >> 6;
    const int tyi = tIdx >> 3, txi = tIdx & 7;
    const int oy2 = tyi < 5 ? 6 * tyi : 30 + 4 * (tyi - 5);
    const int ox2 = txi < 5 ? 6 * txi : 30 + 4 * (txi - 5);
    const int th2 = tyi < 5 ? 6 : 4;
    const int tw2 = txi < 5 ? 6 : 4;
    const int wave = tid >> 6, lane = tid & 63;
    const int pr = lane / 6, pc = lane - 6 * pr;     // plane == lane for lane<36
    const bool act = (pr < th2) && (pc < tw2);
    const int prA = pr > 5 ? 0 : pr, pcA = pc;

    // ---- L3 ownership: group-local. lid3 in [0,256); outputs lid3, lid3+256
    const int lid3 = (bid & 63) * 4 + wave;
    const int kyl = lane / 7, kxl = lane % 7;

    // hoist w3 into registers (t-invariant)
    float w3v[36];
#pragma unroll
    for (int c = 0; c < 36; c++) w3v[c] = (lane < 49) ? w3[c * 49 + lane] : 0.f;

    float m1r[4][2][2];
#pragma unroll
    for (int c = 0; c < 4; c++)
#pragma unroll
        for (int dy = 0; dy < 2; dy++)
#pragma unroll
            for (int dx = 0; dx < 2; dx++) m1r[c][dy][dx] = 0.f;
    float m2r[9];
#pragma unroll
    for (int i = 0; i < 9; i++) m2r[i] = 0.f;
    float m3r[2] = {0.f, 0.f};

    for (int k = 0; k < 12; k++) {
        // ================= A(t=2k), A(t=2k+1) =================
        for (int tt = 0; tt < 2; tt++) {
            const int t = 2 * k + tt;
            if (t >= 20) break;
            uint16_t* s1w = reinterpret_cast<uint16_t*>(s1b + (size_t)(t & 3) * 262144);
            const float* xb = x + ((size_t)t * 8 + b1) * 65536;
            __syncthreads();               // prior xs/st32 readers done
#pragma unroll
            for (int i = 0; i < 9; i++) {
                int idx = tid + i * 256;
                if (idx < 2112) {
                    int row = idx / 264, col = idx - row * 264;
                    int gy = r0 + row - 2, gx = col - 2;
                    float v = 0.f;
                    if (gy >= 0 && gy < 256 && gx >= 0 && gx < 256) v = xb[gy * 256 + gx];
                    u.xs[idx] = v;
                }
            }
            __syncthreads();

            float p[6][6];
#pragma unroll
            for (int i = 0; i < 6; i++)
#pragma unroll
                for (int j = 0; j < 6; j++)
                    p[i][j] = u.xs[(2 * tr + i) * 264 + 2 * tc + j];

            float acc[4][2][2];
#pragma unroll
            for (int c = 0; c < 4; c++)
#pragma unroll
                for (int dy = 0; dy < 2; dy++)
#pragma unroll
                    for (int dx = 0; dx < 2; dx++) acc[c][dy][dx] = 0.f;
#pragma unroll
            for (int c = 0; c < 4; c++)
#pragma unroll
                for (int ky = 0; ky < 5; ky++)
#pragma unroll
                    for (int kx = 0; kx < 5; kx++) {
                        float w = w1[c * 25 + ky * 5 + kx];
#pragma unroll
                        for (int dy = 0; dy < 2; dy++)
#pragma unroll
                            for (int dx = 0; dx < 2; dx++)
                                acc[c][dy][dx] = fmaf(p[dy + ky][dx + kx], w, acc[c][dy][dx]);
                    }

            float mem[4][2][2];
#pragma unroll
            for (int c = 0; c < 4; c++)
#pragma unroll
                for (int dy = 0; dy < 2; dy++)
#pragma unroll
                    for (int dx = 0; dx < 2; dx++)
                        mem[c][dy][dx] = m1r[c][dy][dx] + acc[c][dy][dx];

            int wc[2][2];
#pragma unroll
            for (int dy = 0; dy < 2; dy++)
#pragma unroll
                for (int dx = 0; dx < 2; dx++) {
                    int w = 0; float mx = mem[0][dy][dx];
#pragma unroll
                    for (int c = 1; c < 4; c++) {
                        float v = mem[c][dy][dx];
                        if (v > mx) { mx = v; w = c; }
                    }
                    wc[dy][dx] = w;
                }

            float bm[4];
#pragma unroll
            for (int c = 0; c < 4; c++)
                bm[c] = fmaxf(fmaxf(mem[c][0][0], mem[c][0][1]), fmaxf(mem[c][1][0], mem[c][1][1]));

            uint32_t bits = 0;
#pragma unroll
            for (int c = 0; c < 4; c++)
#pragma unroll
                for (int dy = 0; dy < 2; dy++)
#pragma unroll
                    for (int dx = 0; dx < 2; dx++) {
                        float m = mem[c][dy][dx];
                        bool s = (m >= THR) && (wc[dy][dx] == c) && (m >= bm[c]);
                        m1r[c][dy][dx] = fmaxf((s ? 0.f : m) - 9.0f, 0.f);
                        bits |= (s ? 1u : 0u) << (c * 4 + dy * 2 + dx);
                    }
            stu16(s1w + ((size_t)(b1 * 128 + (r0 >> 1) + tr)) * 128 + tc, (uint16_t)bits);
        }

        // ================= L3(t=2k-4), L3(t=2k-3) : own batch only ========
        for (int tt = 0; tt < 2; tt++) {
            const int tl = 2 * k - 4 + tt;
            if (tl < 0 || tl >= 20) continue;
            const uint32_t* pb32 = reinterpret_cast<const uint32_t*>(
                p2b + (size_t)(tl % 6) * 32768);
#pragma unroll
            for (int rep = 0; rep < 2; rep++) {
                int o = lid3 + rep * 256;
                if (o < 441) {
                    int rr = o / 21, cl = o - rr * 21;
                    int yy = rr + kyl - 3, xx = cl + kxl - 3;
                    bool inb = (lane < 49) && yy >= 0 && yy < 21 && xx >= 0 && xx < 21;
                    uint32_t lo = 0, hi = 0;
                    if (inb) {
                        const uint32_t* pc = pb32 + (((size_t)b2 * 441 + yy * 21 + xx) << 1);
                        lo = ldu32(pc);
                        hi = ldu32(pc + 1);
                    }
                    float accv = 0.f;
#pragma unroll
                    for (int c = 0; c < 32; c++) accv += ((lo >> c) & 1u) ? w3v[c] : 0.f;
#pragma unroll
                    for (int c = 0; c < 4; c++)  accv += ((hi >> c) & 1u) ? w3v[32 + c] : 0.f;
#pragma unroll
                    for (int off = 32; off; off >>= 1) accv += __shfl_xor(accv, off, 64);
                    float memv3 = m3r[rep] + accv;
                    bool s = memv3 >= THR;
                    if (lane == 0) out[(size_t)tl * 3528 + b2 * 441 + o] = s ? 1.f : 0.f;
                    m3r[rep] = fmaxf(s ? 0.f : memv3, 0.f);
                }
            }
        }

        // ================= B(t=2k-2), B(t=2k-1) =================
        for (int tt = 0; tt < 2; tt++) {
            const int tb = 2 * k - 2 + tt;
            if (tb < 0 || tb >= 20) continue;
            const uint32_t* s1r32 = reinterpret_cast<const uint32_t*>(
                s1b + (size_t)(tb & 3) * 262144);
            uint32_t* p2w32 = reinterpret_cast<uint32_t*>(p2b + (size_t)(tb % 6) * 32768);

            const int rb0 = 3 * oy2 - 6;          // s1m block-row base
            const int cb0 = (3 * ox2 - 6) >> 1;   // s1m u32-col base (cw0 even)

            __syncthreads();   // prior LDS readers done; reuse union as st32
#pragma unroll
            for (int i = 0; i < 3; i++) {
                int idx = tid + i * 256;
                if (idx < 527) {
                    int row = idx / 17, w = idx - row * 17;
                    int grow = rb0 + row, gcol = cb0 + w;
                    uint32_t v = 0;
                    if (grow >= 0 && grow < 128 && gcol >= 0 && gcol < 64)
                        v = ldu32(s1r32 + ((size_t)b2 * 128 + grow) * 64 + gcol);
                    u.st32[idx] = v;
                }
            }
            __syncthreads();

            // pool 7x7/6 as bitwise OR with edge nibble-masks -> ps (4 ch at once)
            if (tid < 100) {
                int r = tid / 10, cc2 = tid - 10 * r;
                int gy = oy2 - 2 + r, gx = ox2 - 2 + cc2;
                uint32_t accb = 0;
                if (r < th2 + 4 && cc2 < tw2 + 4 && gy >= 0 && gy < 42 && gx >= 0 && gx < 42) {
                    const uint16_t* st16 = reinterpret_cast<const uint16_t*>(u.st32);
#pragma unroll
                    for (int kr = 0; kr < 4; kr++)
#pragma unroll
                        for (int kc = 0; kc < 4; kc++) {
                            uint32_t m = (kr < 3) ? (kc < 3 ? 0xFu : 0x5u)
                                                  : (kc < 3 ? 0x3u : 0x1u);
                            uint32_t v = st16[(3 * r + kr) * 34 + 3 * cc2 + kc];
                            accb |= v & (m * 0x1111u);
                        }
                }
#pragma unroll
                for (int ic = 0; ic < 4; ic++)
                    ps[ic * 100 + tid] = ((accb >> (4 * ic)) & 0xFu) ? 1.f : 0.f;
            }
            __syncthreads();

            float pv[4][5][5];
#pragma unroll
            for (int ic = 0; ic < 4; ic++)
#pragma unroll
                for (int i = 0; i < 5; i++)
#pragma unroll
                    for (int j = 0; j < 5; j++)
                        pv[ic][i][j] = ps[ic * 100 + (prA + i) * 10 + (pcA + j)];

            float memv[9];
            for (int cc = 0; cc < 9; cc++) {
                int c = cc * 4 + wave;                       // wave-uniform
                const float* wr = w2 + (size_t)__builtin_amdgcn_readfirstlane(c) * 100;
                float accv = 0.f;
#pragma unroll
                for (int ic = 0; ic < 4; ic++)
#pragma unroll
                    for (int i = 0; i < 5; i++)
#pragma unroll
                        for (int j = 0; j < 5; j++)
                            accv = fmaf(pv[ic][i][j], wr[ic * 25 + i * 5 + j], accv);
                float m = act ? (m2r[cc] + accv) : -1e30f;
                memv[cc] = m;
                if (lane < 36) mem_s[c * 36 + lane] = m;     // plane == lane
            }
            __syncthreads();

            if (tid < 36) {
                float mx = mem_s[tid]; int w = 0;
#pragma unroll
                for (int c = 1; c < 36; c++) {
                    float v = mem_s[c * 36 + tid];
                    if (v > mx) { mx = v; w = c; }
                }
                wc_s[tid] = w;
            }
#pragma unroll
            for (int i = 0; i < 2; i++) {
                int idx = tid + i * 256;
                if (idx < 324) {
                    int c = idx / 9, blk = idx - 9 * c;
                    int br = blk / 3, bc2 = blk - 3 * br;
                    int l0 = 12 * br + 2 * bc2;
                    float a = mem_s[c * 36 + l0],     bb2 = mem_s[c * 36 + l0 + 1];
                    float d = mem_s[c * 36 + l0 + 6], e   = mem_s[c * 36 + l0 + 7];
                    bm_s[idx] = fmaxf(fmaxf(a, bb2), fmaxf(d, e));
                }
            }
            if (tid < 18) p2a[tid] = 0;
            __syncthreads();

            const int blkl = (pr >> 1) * 3 + (pc >> 1);
            for (int cc = 0; cc < 9; cc++) {
                int c = cc * 4 + wave;
                if (act) {
                    float m = memv[cc];
                    bool s = (m >= THR) && (wc_s[lane] == c) && (m >= bm_s[c * 9 + blkl]);
                    m2r[cc] = fmaxf((s ? 0.f : m) - 1.0f, 0.f);
                }
            }

#pragma unroll
            for (int i = 0; i < 2; i++) {
                int idx = tid + i * 256;
                if (idx < 324) {
                    int c = idx / 9, blk = idx - 9 * c;
                    int br = blk / 3, bc2 = blk - 3 * br;
                    if (2 * br < th2 && 2 * bc2 < tw2) {
                        int l0 = 12 * br + 2 * bc2;
                        float bmv = bm_s[idx];
                        bool any = false;
#pragma unroll
                        for (int kk = 0; kk < 4; kk++) {
                            int l = l0 + (kk >> 1) * 6 + (kk & 1);
                            float m = mem_s[c * 36 + l];
                            any |= (m >= THR) && (wc_s[l] == c) && (m >= bmv);
                        }
                        if (any)
                            atomicOr(&p2a[(blk << 1) + (c >> 5)], 1u << (c & 31));
                    }
                }
            }
            __syncthreads();

            if (tid < 9) {
                int br = tid / 3, bc2 = tid - 3 * br;
                if (2 * br < th2 && 2 * bc2 < tw2) {
                    int cell = b2 * 441 + ((oy2 >> 1) + br) * 21 + (ox2 >> 1) + bc2;
                    uint32_t* dst = p2w32 + ((size_t)cell << 1);
                    stu32(dst, p2a[tid * 2]);
                    stu32(dst + 1, p2a[tid * 2 + 1]);
                }
            }
        }

        if (k < 11) gbar(bar, bid, ++nbar);
    }
}

extern "C" void kernel_launch(void* const* d_in, const int* in_sizes, int n_in,
                              void* d_out, int out_size, void* d_ws, size_t ws_size,
                              hipStream_t stream) {
    const float* x  = (const float*)d_in[0];
    const float* w1 = (const float*)d_in[1];
    const float* w2 = (const float*)d_in[2];
    const float* w3 = (const float*)d_in[3];
    float* out = (float*)d_out;
    uint8_t* s1 = (uint8_t*)d_ws;
    uint8_t* p2 = (uint8_t*)d_ws + OFF_P2;
    uint32_t* bar = (uint32_t*)((char*)d_ws + OFF_BAR);

    zero_bar<<<1, 256, 0, stream>>>(bar);

    void* args[] = {(void*)&x, (void*)&w1, (void*)&w2, (void*)&w3,
                    (void*)&out, (void*)&s1, (void*)&p2, (void*)&bar};
    hipLaunchCooperativeKernel((void*)spike_persist, dim3(512), dim3(256),
                               args, 0, stream);
}

// Round 9
// 453.465 us; speedup vs baseline: 6.1361x; 1.0125x over previous
//
#include <hip/hip_runtime.h>
#include <stdint.h>

#define THR 10.0f
#define AGT __HIP_MEMORY_SCOPE_AGENT

// ---- workspace layout (bytes) ----
// s1m x8 (u16 bitmask per 2x2 block): 8 * 262,144 = 2,097,152 at 0  (t & 7)
// p2m x8 (2 u32 per cell, 36 ch bits): 8 * 32,768 =   262,144 at 2,097,152 (t & 7)
// barrier: u32[256] at 2,359,296
static constexpr size_t OFF_P2  = 2097152;
static constexpr size_t OFF_BAR = 2359296;

static __device__ __forceinline__ uint32_t ldu32(const uint32_t* p) {
    return __hip_atomic_load(p, __ATOMIC_RELAXED, AGT);
}
static __device__ __forceinline__ void stu32(uint32_t* p, uint32_t v) {
    __hip_atomic_store(p, v, __ATOMIC_RELAXED, AGT);
}
static __device__ __forceinline__ void stu16(uint16_t* p, uint16_t v) {
    __hip_atomic_store(p, v, __ATOMIC_RELAXED, AGT);
}
static __device__ __forceinline__ uint32_t rmwread(uint32_t* p) {
    return __hip_atomic_fetch_add(p, 0u, __ATOMIC_RELAXED, AGT);
}

__global__ __launch_bounds__(256) void zero_bar(uint32_t* __restrict__ bar) {
    if (threadIdx.x < 256) bar[threadIdx.x] = 0u;
}

// Group-local barrier (64 blocks of one batch group); all dataflow is
// intra-group. bar[g*32]: arrival counter; bar[g*32+16]: go epoch.
__device__ __forceinline__ void gbar(uint32_t* bar, int bid, uint32_t n) {
    __syncthreads();                       // drains vmcnt: sc1 stores done
    if (threadIdx.x == 0) {
        uint32_t* base = bar + (bid >> 6) * 32;
        uint32_t a = __hip_atomic_fetch_add(base, 1u, __ATOMIC_RELAXED, AGT);
        if (a == 64u * n - 1u)
            __hip_atomic_fetch_add(base + 16, 1u, __ATOMIC_RELAXED, AGT);
        while (rmwread(base + 16) < n)
            __builtin_amdgcn_s_sleep(2);
    }
    __syncthreads();
}

// Persistent kernel, 512 blocks x 256 threads, 2 blocks/CU.
// Superstep k (k=0..6): A(4k..4k+3) ; L3(4k-8..4k-5) ; B(4k-4..4k-1).
// 6 group-local barriers. All sc1 loads for the superstep are prefetched
// into registers right after the barrier (latency paid once, behind A).
__global__ __launch_bounds__(256, 2) void spike_persist(
    const float* __restrict__ x,    // (20,8,1,256,256)
    const float* __restrict__ w1,   // (4,1,5,5)
    const float* __restrict__ w2,   // (36,4,5,5)
    const float* __restrict__ w3,   // (1,36,7,7)
    float* __restrict__ out,        // (20,8,1,21,21)
    uint8_t* __restrict__ s1b,      // 8 buffers of u16[8][128][128]
    uint8_t* __restrict__ p2b,      // 8 buffers of u32[8][441][2]
    uint32_t* __restrict__ bar)
{
    __shared__ union {
        float    xs[2112];           // phase A: 8 x 264 input rows (halo 2)
        uint32_t st32[527];          // phase B: staged s1m 31 rows x 17 u32
    } u;
    __shared__ float    ps[400];     // 4 x 10 x 10 pooled p1 tile (halo 2)
    __shared__ float    mem_s[1296]; // 36 ch x 36 planes (pitch 6)
    __shared__ float    bm_s[324];   // 36 ch x 9 blocks (pitch 3)
    __shared__ int      wc_s[36];
    __shared__ uint32_t p2a[18];     // 9 blocks x 2 words of channel bits

    const int tid = threadIdx.x;
    const int bid = blockIdx.x;
    uint32_t nbar = 0;

    // ---- L1 ownership: 512 blocks = 8 b x 64 row-strips (4 rows each)
    const int b1 = bid >> 6;
    const int r0 = (bid & 63) * 4;
    const int tr = tid >> 7, tc = tid & 127;

    // ---- L2 ownership: 512 blocks = 8 b x 64 tiles (8x8, uneven splits)
    const int tIdx = bid & 63;
    const int b2 = bid >> 6;
    const int tyi = tIdx >> 3, txi = tIdx & 7;
    const int oy2 = tyi < 5 ? 6 * tyi : 30 + 4 * (tyi - 5);
    const int ox2 = txi < 5 ? 6 * txi : 30 + 4 * (txi - 5);
    const int th2 = tyi < 5 ? 6 : 4;
    const int tw2 = txi < 5 ? 6 : 4;
    const int wave = tid >> 6, lane = tid & 63;
    const int pr = lane / 6, pc = lane - 6 * pr;     // plane == lane for lane<36
    const bool act = (pr < th2) && (pc < tw2);
    const int prA = pr > 5 ? 0 : pr, pcA = pc;

    // ---- L3 ownership: group-local. lid3 in [0,256); outputs lid3, lid3+256
    const int lid3 = (bid & 63) * 4 + wave;
    const int kyl = lane / 7, kxl = lane % 7;

    // hoist w3 into registers (t-invariant)
    float w3v[36];
#pragma unroll
    for (int c = 0; c < 36; c++) w3v[c] = (lane < 49) ? w3[c * 49 + lane] : 0.f;

    // ---- t-invariant address precompute ----
    int aoff[9]; bool aval[9];
#pragma unroll
    for (int i = 0; i < 9; i++) {
        int idx = tid + i * 256;
        int row = idx / 264, col = idx - row * 264;
        int gy = r0 + row - 2, gx = col - 2;
        aval[i] = (idx < 2112) && gy >= 0 && gy < 256 && gx >= 0 && gx < 256;
        aoff[i] = gy * 256 + gx;
    }
    const size_t s1soff = ((size_t)(b1 * 128 + (r0 >> 1) + tr)) * 128 + tc;

    const int rb0 = 3 * oy2 - 6;
    const int cb0 = (3 * ox2 - 6) >> 1;
    int boff[3]; bool bval[3];
#pragma unroll
    for (int i = 0; i < 3; i++) {
        int idx = tid + i * 256;
        int row = idx / 17, w = idx - row * 17;
        int grow = rb0 + row, gcol = cb0 + w;
        bval[i] = (idx < 527) && grow >= 0 && grow < 128 && gcol >= 0 && gcol < 64;
        boff[i] = (b2 * 128 + grow) * 64 + gcol;
    }

    bool l3in[2], l3v[2]; int l3o[2];
#pragma unroll
    for (int rep = 0; rep < 2; rep++) {
        int o = lid3 + rep * 256;
        int rr = o / 21, cl = o - rr * 21;
        int yy = rr + kyl - 3, xx = cl + kxl - 3;
        l3in[rep] = o < 441;
        l3v[rep] = (o < 441) && (lane < 49) && yy >= 0 && yy < 21 && xx >= 0 && xx < 21;
        l3o[rep] = (b2 * 441 + yy * 21 + xx) << 1;
    }

    float m1r[4][2][2];
#pragma unroll
    for (int c = 0; c < 4; c++)
#pragma unroll
        for (int dy = 0; dy < 2; dy++)
#pragma unroll
            for (int dx = 0; dx < 2; dx++) m1r[c][dy][dx] = 0.f;
    float m2r[9];
#pragma unroll
    for (int i = 0; i < 9; i++) m2r[i] = 0.f;
    float m3r[2] = {0.f, 0.f};

    for (int k = 0; k < 7; k++) {
        // ---------- prefetch all sc1 loads for this superstep ----------
        uint32_t pfB[4][3];
#pragma unroll
        for (int tt = 0; tt < 4; tt++) {
            int tb = 4 * k - 4 + tt;
            if (tb >= 0 && tb < 20) {
                const uint32_t* s1r32 = reinterpret_cast<const uint32_t*>(
                    s1b + (size_t)(tb & 7) * 262144);
#pragma unroll
                for (int i = 0; i < 3; i++)
                    pfB[tt][i] = bval[i] ? ldu32(s1r32 + boff[i]) : 0u;
            }
        }
        uint32_t pfLlo[4][2], pfLhi[4][2];
#pragma unroll
        for (int tt = 0; tt < 4; tt++) {
            int tl = 4 * k - 8 + tt;
            if (tl >= 0 && tl < 20) {
                const uint32_t* pb32 = reinterpret_cast<const uint32_t*>(
                    p2b + (size_t)(tl & 7) * 32768);
#pragma unroll
                for (int rep = 0; rep < 2; rep++) {
                    pfLlo[tt][rep] = l3v[rep] ? ldu32(pb32 + l3o[rep]) : 0u;
                    pfLhi[tt][rep] = l3v[rep] ? ldu32(pb32 + l3o[rep] + 1) : 0u;
                }
            }
        }

        // ================= A(t=4k .. 4k+3) =================
#pragma unroll
        for (int tt = 0; tt < 4; tt++) {
            const int t = 4 * k + tt;
            if (t < 20) {
                uint16_t* s1w = reinterpret_cast<uint16_t*>(s1b + (size_t)(t & 7) * 262144);
                const float* xb = x + ((size_t)t * 8 + b1) * 65536;
                __syncthreads();               // prior xs/st32 readers done
#pragma unroll
                for (int i = 0; i < 9; i++) {
                    int idx = tid + i * 256;
                    if (idx < 2112) u.xs[idx] = aval[i] ? xb[aoff[i]] : 0.f;
                }
                __syncthreads();

                const float2* xs2 = reinterpret_cast<const float2*>(u.xs);
                float p[6][6];
#pragma unroll
                for (int i = 0; i < 6; i++)
#pragma unroll
                    for (int j = 0; j < 3; j++) {
                        float2 v = xs2[(2 * tr + i) * 132 + tc + j];
                        p[i][2 * j] = v.x; p[i][2 * j + 1] = v.y;
                    }

                float acc[4][2][2];
#pragma unroll
                for (int c = 0; c < 4; c++)
#pragma unroll
                    for (int dy = 0; dy < 2; dy++)
#pragma unroll
                        for (int dx = 0; dx < 2; dx++) acc[c][dy][dx] = 0.f;
#pragma unroll
                for (int c = 0; c < 4; c++)
#pragma unroll
                    for (int ky = 0; ky < 5; ky++)
#pragma unroll
                        for (int kx = 0; kx < 5; kx++) {
                            float w = w1[c * 25 + ky * 5 + kx];
#pragma unroll
                            for (int dy = 0; dy < 2; dy++)
#pragma unroll
                                for (int dx = 0; dx < 2; dx++)
                                    acc[c][dy][dx] = fmaf(p[dy + ky][dx + kx], w, acc[c][dy][dx]);
                        }

                float mem[4][2][2];
#pragma unroll
                for (int c = 0; c < 4; c++)
#pragma unroll
                    for (int dy = 0; dy < 2; dy++)
#pragma unroll
                        for (int dx = 0; dx < 2; dx++)
                            mem[c][dy][dx] = m1r[c][dy][dx] + acc[c][dy][dx];

                int wc[2][2];
#pragma unroll
                for (int dy = 0; dy < 2; dy++)
#pragma unroll
                    for (int dx = 0; dx < 2; dx++) {
                        int w = 0; float mx = mem[0][dy][dx];
#pragma unroll
                        for (int c = 1; c < 4; c++) {
                            float v = mem[c][dy][dx];
                            if (v > mx) { mx = v; w = c; }
                        }
                        wc[dy][dx] = w;
                    }

                float bm[4];
#pragma unroll
                for (int c = 0; c < 4; c++)
                    bm[c] = fmaxf(fmaxf(mem[c][0][0], mem[c][0][1]),
                                  fmaxf(mem[c][1][0], mem[c][1][1]));

                uint32_t bits = 0;
#pragma unroll
                for (int c = 0; c < 4; c++)
#pragma unroll
                    for (int dy = 0; dy < 2; dy++)
#pragma unroll
                        for (int dx = 0; dx < 2; dx++) {
                            float m = mem[c][dy][dx];
                            bool s = (m >= THR) && (wc[dy][dx] == c) && (m >= bm[c]);
                            m1r[c][dy][dx] = fmaxf((s ? 0.f : m) - 9.0f, 0.f);
                            bits |= (s ? 1u : 0u) << (c * 4 + dy * 2 + dx);
                        }
                stu16(reinterpret_cast<uint16_t*>(s1w) + s1soff, (uint16_t)bits);
            }
        }

        // ================= L3(t=4k-8 .. 4k-5) =================
#pragma unroll
        for (int tt = 0; tt < 4; tt++) {
            const int tl = 4 * k - 8 + tt;
            if (tl >= 0 && tl < 20) {
#pragma unroll
                for (int rep = 0; rep < 2; rep++) {
                    if (l3in[rep]) {
                        int o = lid3 + rep * 256;
                        uint32_t lo = pfLlo[tt][rep], hi = pfLhi[tt][rep];
                        float accv = 0.f;
#pragma unroll
                        for (int c = 0; c < 32; c++) accv += ((lo >> c) & 1u) ? w3v[c] : 0.f;
#pragma unroll
                        for (int c = 0; c < 4; c++)  accv += ((hi >> c) & 1u) ? w3v[32 + c] : 0.f;
#pragma unroll
                        for (int off = 32; off; off >>= 1) accv += __shfl_xor(accv, off, 64);
                        float memv3 = m3r[rep] + accv;
                        bool s = memv3 >= THR;
                        if (lane == 0) out[(size_t)tl * 3528 + b2 * 441 + o] = s ? 1.f : 0.f;
                        m3r[rep] = fmaxf(s ? 0.f : memv3, 0.f);
                    }
                }
            }
        }

        // ================= B(t=4k-4 .. 4k-1) =================
#pragma unroll
        for (int tt = 0; tt < 4; tt++) {
            const int tb = 4 * k - 4 + tt;
            if (tb >= 0 && tb < 20) {
                uint32_t* p2w32 = reinterpret_cast<uint32_t*>(p2b + (size_t)(tb & 7) * 32768);

                __syncthreads();   // prior LDS readers done; reuse union as st32
#pragma unroll
                for (int i = 0; i < 3; i++) {
                    int idx = tid + i * 256;
                    if (idx < 527) u.st32[idx] = pfB[tt][i];
                }
                __syncthreads();

                // pool 7x7/6 as bitwise OR with edge nibble-masks -> ps
                if (tid < 100) {
                    int r = tid / 10, cc2 = tid - 10 * r;
                    int gy = oy2 - 2 + r, gx = ox2 - 2 + cc2;
                    uint32_t accb = 0;
                    if (r < th2 + 4 && cc2 < tw2 + 4 && gy >= 0 && gy < 42 && gx >= 0 && gx < 42) {
                        const uint16_t* st16 = reinterpret_cast<const uint16_t*>(u.st32);
#pragma unroll
                        for (int kr = 0; kr < 4; kr++)
#pragma unroll
                            for (int kc = 0; kc < 4; kc++) {
                                uint32_t m = (kr < 3) ? (kc < 3 ? 0xFu : 0x5u)
                                                      : (kc < 3 ? 0x3u : 0x1u);
                                uint32_t v = st16[(3 * r + kr) * 34 + 3 * cc2 + kc];
                                accb |= v & (m * 0x1111u);
                            }
                    }
#pragma unroll
                    for (int ic = 0; ic < 4; ic++)
                        ps[ic * 100 + tid] = ((accb >> (4 * ic)) & 0xFu) ? 1.f : 0.f;
                }
                __syncthreads();

                float pv[4][5][5];
#pragma unroll
                for (int ic = 0; ic < 4; ic++)
#pragma unroll
                    for (int i = 0; i < 5; i++)
#pragma unroll
                        for (int j = 0; j < 5; j++)
                            pv[ic][i][j] = ps[ic * 100 + (prA + i) * 10 + (pcA + j)];

                float memv[9];
                for (int cc = 0; cc < 9; cc++) {
                    int c = cc * 4 + wave;                       // wave-uniform
                    const float* wr = w2 + (size_t)__builtin_amdgcn_readfirstlane(c) * 100;
                    float accv = 0.f;
#pragma unroll
                    for (int ic = 0; ic < 4; ic++)
#pragma unroll
                        for (int i = 0; i < 5; i++)
#pragma unroll
                            for (int j = 0; j < 5; j++)
                                accv = fmaf(pv[ic][i][j], wr[ic * 25 + i * 5 + j], accv);
                    float m = act ? (m2r[cc] + accv) : -1e30f;
                    memv[cc] = m;
                    if (lane < 36) mem_s[c * 36 + lane] = m;     // plane == lane
                }
                __syncthreads();

                if (tid < 36) {
                    float mx = mem_s[tid]; int w = 0;
#pragma unroll
                    for (int c = 1; c < 36; c++) {
                        float v = mem_s[c * 36 + tid];
                        if (v > mx) { mx = v; w = c; }
                    }
                    wc_s[tid] = w;
                }
#pragma unroll
                for (int i = 0; i < 2; i++) {
                    int idx = tid + i * 256;
                    if (idx < 324) {
                        int c = idx / 9, blk = idx - 9 * c;
                        int br = blk / 3, bc2 = blk - 3 * br;
                        int l0 = 12 * br + 2 * bc2;
                        float a = mem_s[c * 36 + l0],     bb2 = mem_s[c * 36 + l0 + 1];
                        float d = mem_s[c * 36 + l0 + 6], e   = mem_s[c * 36 + l0 + 7];
                        bm_s[idx] = fmaxf(fmaxf(a, bb2), fmaxf(d, e));
                    }
                }
                if (tid < 18) p2a[tid] = 0;
                __syncthreads();

                const int blkl = (pr >> 1) * 3 + (pc >> 1);
                for (int cc = 0; cc < 9; cc++) {
                    int c = cc * 4 + wave;
                    if (act) {
                        float m = memv[cc];
                        bool s = (m >= THR) && (wc_s[lane] == c) && (m >= bm_s[c * 9 + blkl]);
                        m2r[cc] = fmaxf((s ? 0.f : m) - 1.0f, 0.f);
                    }
                }

#pragma unroll
                for (int i = 0; i < 2; i++) {
                    int idx = tid + i * 256;
                    if (idx < 324) {
                        int c = idx / 9, blk = idx - 9 * c;
                        int br = blk / 3, bc2 = blk - 3 * br;
                        if (2 * br < th2 && 2 * bc2 < tw2) {
                            int l0 = 12 * br + 2 * bc2;
                            float bmv = bm_s[idx];
                            bool any = false;
#pragma unroll
                            for (int kk = 0; kk < 4; kk++) {
                                int l = l0 + (kk >> 1) * 6 + (kk & 1);
                                float m = mem_s[c * 36 + l];
                                any |= (m >= THR) && (wc_s[l] == c) && (m >= bmv);
                            }
                            if (any)
                                atomicOr(&p2a[(blk << 1) + (c >> 5)], 1u << (c & 31));
                        }
                    }
                }
                __syncthreads();

                if (tid < 9) {
                    int br = tid / 3, bc2 = tid - 3 * br;
                    if (2 * br < th2 && 2 * bc2 < tw2) {
                        int cell = b2 * 441 + ((oy2 >> 1) + br) * 21 + (ox2 >> 1) + bc2;
                        uint32_t* dst = p2w32 + ((size_t)cell << 1);
                        stu32(dst, p2a[tid * 2]);
                        stu32(dst + 1, p2a[tid * 2 + 1]);
                    }
                }
            }
        }

        if (k < 6) gbar(bar, bid, ++nbar);
    }
}

extern "C" void kernel_launch(void* const* d_in, const int* in_sizes, int n_in,
                              void* d_out, int out_size, void* d_ws, size_t ws_size,
                              hipStream_t stream) {
    const float* x  = (const float*)d_in[0];
    const float* w1 = (const float*)d_in[1];
    const float* w2 = (const float*)d_in[2];
    const float* w3 = (const float*)d_in[3];
    float* out = (float*)d_out;
    uint8_t* s1 = (uint8_t*)d_ws;
    uint8_t* p2 = (uint8_t*)d_ws + OFF_P2;
    uint32_t* bar = (uint32_t*)((char*)d_ws + OFF_BAR);

    zero_bar<<<1, 256, 0, stream>>>(bar);

    void* args[] = {(void*)&x, (void*)&w1, (void*)&w2, (void*)&w3,
                    (void*)&out, (void*)&s1, (void*)&p2, (void*)&bar};
    hipLaunchCooperativeKernel((void*)spike_persist, dim3(512), dim3(256),
                               args, 0, stream);
}